// Round 13
// baseline (806.968 us; speedup 1.0000x reference)
//
#include <hip/hip_runtime.h>
#include <hip/hip_bf16.h>

// Problem constants (fixed instance)
#define N_NODES 4096
#define CF      256
#define CIN     64
#define E0_EDGES 65536
#define NLAYER  8
#define NOUT    1024
#define CN      (CF * N_NODES)
#define STD_BLOCKS 64

typedef unsigned short ushort;
typedef __attribute__((ext_vector_type(8))) short s8v;   // 8 bf16
typedef __attribute__((ext_vector_type(4))) float f4v;   // MFMA acc

__device__ __forceinline__ ushort f2bf(float x){
  unsigned int u = __builtin_bit_cast(unsigned int, x);
  return (ushort)((u + 0x7FFFu + ((u >> 16) & 1u)) >> 16);
}
__device__ __forceinline__ float bf2f(ushort h){
  unsigned int u = ((unsigned int)h) << 16;
  return __builtin_bit_cast(float, u);
}

// ---------------- reduction helpers ----------------
__device__ __forceinline__ float waveSumF(float v){
  #pragma unroll
  for (int o = 32; o; o >>= 1) v += __shfl_xor(v, o);
  return v;
}
__device__ __forceinline__ double waveSumD(double v){
  #pragma unroll
  for (int o = 32; o; o >>= 1) v += __shfl_xor(v, o);
  return v;
}
__device__ __forceinline__ float waveMaxF(float v){
  #pragma unroll
  for (int o = 32; o; o >>= 1) v = fmaxf(v, __shfl_xor(v, o));
  return v;
}
__device__ float blockSumF(float v){
  __shared__ float sm[4];
  v = waveSumF(v);
  int l = threadIdx.x & 63, w = threadIdx.x >> 6;
  __syncthreads();
  if (l == 0) sm[w] = v;
  __syncthreads();
  return sm[0] + sm[1] + sm[2] + sm[3];
}
__device__ double blockSumD(double v){
  __shared__ double sm[4];
  v = waveSumD(v);
  int l = threadIdx.x & 63, w = threadIdx.x >> 6;
  __syncthreads();
  if (l == 0) sm[w] = v;
  __syncthreads();
  return sm[0] + sm[1] + sm[2] + sm[3];
}
__device__ float blockMaxF(float v){
  __shared__ float sm[4];
  v = waveMaxF(v);
  int l = threadIdx.x & 63, w = threadIdx.x >> 6;
  __syncthreads();
  if (l == 0) sm[w] = v;
  __syncthreads();
  return fmaxf(fmaxf(sm[0], sm[1]), fmaxf(sm[2], sm[3]));
}

// ---------------- bf16 MFMA GEMM, depth-2 prefetch, templated N-tile ---------
// C[M,N] = alpha*A·B^T (+beta*Cf, +bias, act). A,B bf16 row-major K-contiguous.
// A rows split across A1/A2 at K=splitAt. Tile 64xNT (NT=64 or 32); 4 waves as
// 2x2 (wave-tile 32 x NT/2). NT=32 -> grid.x = N/32 = 2x blocks -> 2 blocks/CU
// co-resident (52KB LDS), so one block's loads overlap the other's MFMA.
// Loads issued two tiles ahead (static ping-pong regs). One barrier per tile.
// WFH: extra transposed bf16 write. TRI: upper-triangle 64x64 tiles of 256².
// cStrideZ!=0: per-z split-K partials (plain store).
// NOTE (R9): do NOT fuse tanh into STORETILE (critical-path VALU, ~3x cost).
// NOTE (R10): keep edgeW at 4 edges/wave; L2-resident redundancy is free,
// serialized wave chains are not.
#define MF(a,b,c) c = __builtin_amdgcn_mfma_f32_16x16x32_bf16(a, b, c, 0, 0, 0)

template<int BK, int NT, int ACT, bool WF32, bool WBF, bool WFH, bool MV, bool TRI>
__global__ __launch_bounds__(256)
void gemmB1(const ushort* __restrict__ A1, const ushort* __restrict__ A2,
            int lda, int splitAt,
            const ushort* __restrict__ B, int ldb,
            float* __restrict__ Cf, ushort* __restrict__ Cb, ushort* __restrict__ Cfh,
            int ldc, size_t cStrideZ, int kChunk,
            float alpha, float beta, const float* __restrict__ bias,
            double* __restrict__ pS, double* __restrict__ pS2)
{
  constexpr int BR  = (NT == 64) ? 64 : 32;       // B-tile rows (output cols)
  constexpr int NCA = BK / 32;                    // A s8v chunks per thread
  constexpr int NCB = (NT == 64) ? BK / 32 : BK / 64;
  __shared__ ushort As[2][64][BK + 8], Bs[2][BR][BK + 8];
  const int tid = threadIdx.x;
  const int ar = tid >> 2, ak = (tid & 3) * (BK / 4);
  const int br = (NT == 64) ? (tid >> 2) : (tid >> 3);
  const int bk_ = (NT == 64) ? ak : (tid & 7) * (BK / 8);
  int bx = blockIdx.x, by = blockIdx.y;
  if (TRI) {
    const int trT[10] = {0,0,0,0,1,1,1,2,2,3};
    const int tcT[10] = {0,1,2,3,1,2,3,2,3,3};
    by = trT[blockIdx.x]; bx = tcT[blockIdx.x];
  }
  const int row0 = by * 64, col0 = bx * NT;
  const int kStart = blockIdx.z * kChunk;
  const int nT = kChunk / BK;

  const int wid = tid >> 6, lane = tid & 63;
  const int wr = (wid >> 1) * 32, wc = (wid & 1) * (NT / 2);
  const int fr = lane & 15, fk = (lane >> 4) * 8;

  f4v acc[2][NT / 32] = {};
  s8v rA0[NCA], rB0[NCB], rA1[NCA], rB1[NCB];

#define LOADTILE(T, RA, RB) { \
    int k0 = kStart + (T) * BK; \
    const ushort* Ag; int kk; \
    if (k0 < splitAt) { Ag = A1; kk = k0; } else { Ag = A2; kk = k0 - splitAt; } \
    size_t aoff = (size_t)(row0 + ar) * lda + kk + ak; \
    size_t boff = (size_t)(col0 + br) * ldb + k0 + bk_; \
    _Pragma("unroll") \
    for (int c = 0; c < NCA; c++) RA[c] = *(const s8v*)(Ag + aoff + 8 * c); \
    _Pragma("unroll") \
    for (int c = 0; c < NCB; c++) RB[c] = *(const s8v*)(B + boff + 8 * c); }

#define STORETILE(BUF, RA, RB) { \
    _Pragma("unroll") \
    for (int c = 0; c < NCA; c++) *(s8v*)&As[BUF][ar][ak + 8 * c] = RA[c]; \
    _Pragma("unroll") \
    for (int c = 0; c < NCB; c++) *(s8v*)&Bs[BUF][br][bk_ + 8 * c] = RB[c]; }

#define MFMAT(BUF) { \
    _Pragma("unroll") \
    for (int ks = 0; ks < BK; ks += 32) { \
      s8v a0 = *(const s8v*)&As[BUF][wr + fr][ks + fk]; \
      s8v a1 = *(const s8v*)&As[BUF][wr + 16 + fr][ks + fk]; \
      s8v b0 = *(const s8v*)&Bs[BUF][wc + fr][ks + fk]; \
      MF(a0, b0, acc[0][0]); \
      MF(a1, b0, acc[1][0]); \
      if constexpr (NT == 64) { \
        s8v b1 = *(const s8v*)&Bs[BUF][wc + 16 + fr][ks + fk]; \
        MF(a0, b1, acc[0][1]); \
        MF(a1, b1, acc[1][1]); } } }

  LOADTILE(0, rA0, rB0);
  if (nT > 1) LOADTILE(1, rA1, rB1);
  STORETILE(0, rA0, rB0);

  for (int t = 0; t < nT; t += 2) {
    __syncthreads();                       // lds0(tile t) visible; old reads done
    if (t + 2 < nT) LOADTILE(t + 2, rA0, rB0);
    MFMAT(0);
    if (t + 1 < nT) {
      STORETILE(1, rA1, rB1);              // lds1 last read before top barrier
      __syncthreads();
      if (t + 3 < nT) LOADTILE(t + 3, rA1, rB1);
      MFMAT(1);
      if (t + 2 < nT) STORETILE(0, rA0, rB0);  // lds0 last read before mid barrier
    }
  }
#undef LOADTILE
#undef STORETILE
#undef MFMAT

  double s = 0, s2 = 0;
  #pragma unroll
  for (int m = 0; m < 2; m++)
    #pragma unroll
    for (int n = 0; n < NT / 32; n++) {
      const int rowb = row0 + wr + m * 16 + (lane >> 4) * 4;
      const int col  = col0 + wc + n * 16 + fr;
      ushort4 hv;
      #pragma unroll
      for (int q = 0; q < 4; q++) {
        size_t cidx = (size_t)(rowb + q) * ldc + col;
        float v = alpha * acc[m][n][q];
        if (cStrideZ) {
          Cf[blockIdx.z * cStrideZ + cidx] = v;
        } else {
          if (beta != 0.0f) v += beta * Cf[cidx];
          if (bias) v += bias[col];
          if (ACT == 1) v = (v > 0.0f) ? v : expm1f(v);
          if (WF32) Cf[cidx] = v;
          if (WBF)  Cb[cidx] = f2bf(v);
          if (WFH)  ((ushort*)&hv)[q] = f2bf(v);
          if (MV)   { s += v; s2 += (double)v * v; }
        }
      }
      if (WFH && !cStrideZ)
        *(ushort4*)(Cfh + (size_t)col * N_NODES + rowb) = hv;
    }
  if (MV) {
    s  = blockSumD(s);
    s2 = blockSumD(s2);
    if (tid == 0) {
      int bid = blockIdx.y * gridDim.x + blockIdx.x;   // stats grids are <=512 blocks
      pS[bid] = s; pS2[bid] = s2;
    }
  }
}

// ---------------- weight f32 -> bf16 (once per launch) ----------------------
#define OFF_K1   0
#define OFF_K2   16384
#define OFF_KNC  81920
#define OFF_KN1  147456
#define OFF_KN2  1196032
#define OFF_L1   1720320
#define OFF_L2   1785856
#define NW_TOT   2048000

__global__ __launch_bounds__(256)
void prepWK(const float* s0, const float* s1, const float* s2, const float* s3,
            const float* s4, const float* s5, const float* s6,
            ushort* __restrict__ h)
{
  const int sizes[7] = {16384, 65536, 65536, 1048576, 524288, 65536, 262144};
  const int offs[7]  = {OFF_K1, OFF_K2, OFF_KNC, OFF_KN1, OFF_KN2, OFF_L1, OFF_L2};
  int seg = blockIdx.y;
  const float* src = seg==0?s0: seg==1?s1: seg==2?s2: seg==3?s3: seg==4?s4: seg==5?s5: s6;
  int n = sizes[seg], off = offs[seg];
  for (int i = blockIdx.x * 256 + threadIdx.x; i < n; i += gridDim.x * 256)
    h[off + i] = f2bf(src[i]);
}

// ---------------- transpose f32 [R][Cc] -> bf16 [Cc][R] (open only) ----------
__global__ __launch_bounds__(256)
void transposeBF(const float* __restrict__ in, ushort* __restrict__ outh, int R, int Cc)
{
  __shared__ float t[32][33];
  int x  = blockIdx.x * 32 + threadIdx.x;
  int y0 = blockIdx.y * 32;
  for (int dy = threadIdx.y; dy < 32; dy += 8)
    t[dy][threadIdx.x] = in[(size_t)(y0 + dy) * Cc + x];
  __syncthreads();
  int ox  = y0 + threadIdx.x;
  int oy0 = blockIdx.x * 32;
  for (int dy = threadIdx.y; dy < 32; dy += 8)
    outh[(size_t)(oy0 + dy) * R + ox] = f2bf(t[threadIdx.x][dy]);
}

// ---------------- whole-tensor tanh-LN in place on bf16 ---------------------
// Stats partial arrays are 512 entries (NT=32 GEMM grids).
__global__ __launch_bounds__(256)
void tanhNormBF(ushort* __restrict__ h, const double* __restrict__ pS,
                const double* __restrict__ pS2)
{
  __shared__ float bc[2];
  double a = pS[threadIdx.x] + pS[threadIdx.x + 256];
  double b = pS2[threadIdx.x] + pS2[threadIdx.x + 256];
  a = blockSumD(a);
  b = blockSumD(b);
  if (threadIdx.x == 0) {
    double m   = a / (double)CN;
    double var = b / (double)CN - m * m;
    bc[0] = (float)m;
    bc[1] = (float)(1.0 / sqrt(var + 1e-5));
  }
  __syncthreads();
  float mf = bc[0], rs = bc[1];
  for (size_t i = ((size_t)blockIdx.x * 256 + threadIdx.x) * 8; i < CN;
       i += (size_t)256 * 256 * 8) {
    s8v hv = *(s8v*)(h + i);
    #pragma unroll
    for (int k = 0; k < 8; k++) {
      float x = bf2f((ushort)hv[k]);
      x = tanhf((x - mf) * rs);
      hv[k] = (short)f2bf(x);
    }
    *(s8v*)(h + i) = hv;
  }
}

// ---------------- fused sq + s/h partials + deg zero (bf16 in) ---------------
__global__ __launch_bounds__(256)
void sqSHK(const ushort* __restrict__ fTh, float* __restrict__ sq,
           float* __restrict__ sP, float* __restrict__ hP, float* __restrict__ deg)
{
  __shared__ float smS[4][256], smH[4][256];
  int b = blockIdx.x, w = threadIdx.x >> 6, lane = threadIdx.x & 63;
  if (threadIdx.x < 64) deg[b * 64 + threadIdx.x] = 0.0f;
  float sA[4] = {0,0,0,0}, hA[4] = {0,0,0,0};
  for (int rr = 0; rr < 16; rr++) {
    int n = b * 64 + rr * 4 + w;
    ushort4 u = ((const ushort4*)(fTh + (size_t)n * CF))[lane];
    float x0 = bf2f(u.x), x1 = bf2f(u.y), x2 = bf2f(u.z), x3 = bf2f(u.w);
    float q = waveSumF(x0*x0 + x1*x1 + x2*x2 + x3*x3);
    if (lane == 0) sq[n] = q;
    sA[0] += x0; sA[1] += x1; sA[2] += x2; sA[3] += x3;
    hA[0] += x0*q; hA[1] += x1*q; hA[2] += x2*q; hA[3] += x3*q;
  }
  #pragma unroll
  for (int k = 0; k < 4; k++) { smS[w][lane*4+k] = sA[k]; smH[w][lane*4+k] = hA[k]; }
  __syncthreads();
  int t = threadIdx.x;
  sP[(size_t)b * 256 + t] = smS[0][t] + smS[1][t] + smS[2][t] + smS[3][t];
  hP[(size_t)b * 256 + t] = smH[0][t] + smH[1][t] + smH[2][t] + smH[3][t];
}

// ---------------- std(D) closed form: 64-block partials (upper-tri Gp) -------
__global__ __launch_bounds__(256)
void stdPartsK(const float* __restrict__ sP, const float* __restrict__ hP,
               const float* __restrict__ Gp, const float* __restrict__ sq,
               double* __restrict__ parts)
{
  int b = blockIdx.x, t = threadIdx.x;
  double S1 = 0, S2 = 0, sd = 0, hd = 0, gf = 0;
  for (int i = b * 256 + t; i < N_NODES; i += STD_BLOCKS * 256) {
    double q = sq[i]; S1 += q; S2 += q * q;
  }
  if (b == 0) {
    float sv = 0, hv = 0;
    for (int p = 0; p < 64; p++) { sv += sP[p * 256 + t]; hv += hP[p * 256 + t]; }
    sd = (double)sv * sv; hd = (double)hv * sv;
  }
  for (int i = b * 256 + t; i < CF * CF; i += STD_BLOCKS * 256) {
    int r = i >> 8, c = i & 255;
    if (r > c) continue;               // only upper-triangle tiles were computed
    double g = 0;
    #pragma unroll 4
    for (int z = 0; z < 16; z++) g += Gp[(size_t)z * 65536 + i];
    gf += (r == c) ? g * g : 2.0 * g * g;
  }
  S1 = blockSumD(S1);
  S2 = blockSumD(S2);
  sd = blockSumD(sd);
  hd = blockSumD(hd);
  gf = blockSumD(gf);
  if (t == 0) {
    parts[0 * STD_BLOCKS + b] = S1;
    parts[1 * STD_BLOCKS + b] = S2;
    parts[2 * STD_BLOCKS + b] = sd;
    parts[3 * STD_BLOCKS + b] = hd;
    parts[4 * STD_BLOCKS + b] = gf;
  }
}

// ---------------- edge affinities + inline std finalize + deg atomics --------
// 4096 blocks, 4 edges per wave.
__global__ __launch_bounds__(256)
void edgeWK(const int* __restrict__ ei, const int* __restrict__ ej,
            const ushort* __restrict__ fTh, const float* __restrict__ sq,
            const double* __restrict__ parts, float* __restrict__ wE,
            float* __restrict__ deg)
{
  __shared__ float c0s;
  if (threadIdx.x < 64) {
    int l = threadIdx.x;
    double v0 = waveSumD(parts[0 * STD_BLOCKS + l]);
    double v1 = waveSumD(parts[1 * STD_BLOCKS + l]);
    double v2 = waveSumD(parts[2 * STD_BLOCKS + l]);
    double v3 = waveSumD(parts[3 * STD_BLOCKS + l]);
    double v4 = waveSumD(parts[4 * STD_BLOCKS + l]);
    if (l == 0) {
      double NN = (double)N_NODES;
      double sum1 = 2.0 * NN * v0 - 2.0 * v2;
      double sum2 = 2.0 * NN * v1 + 2.0 * v0 * v0 + 4.0 * v4 - 8.0 * v3;
      double n2 = NN * NN;
      double var = (sum2 - sum1 * sum1 / n2) / (n2 - 1.0);
      double sdev = sqrt(var > 0 ? var : 0);
      c0s = (float)(-2.0 / sdev);
    }
  }
  __syncthreads();
  float c0 = c0s;
  int w = threadIdx.x >> 6, lane = threadIdx.x & 63;
  int e0 = (blockIdx.x * 4 + w) * 4;
  for (int q = 0; q < 4; q++) {
    int e = e0 + q;
    int i = ei[e], j = ej[e];
    ushort4 ua = ((const ushort4*)(fTh + (size_t)i * CF))[lane];
    ushort4 ub = ((const ushort4*)(fTh + (size_t)j * CF))[lane];
    float d = waveSumF(bf2f(ua.x)*bf2f(ub.x) + bf2f(ua.y)*bf2f(ub.y) +
                       bf2f(ua.z)*bf2f(ub.z) + bf2f(ua.w)*bf2f(ub.w));
    if (lane == 0) {
      float dist = fmaxf(sq[i] + sq[j] - 2.0f * d, 0.0f);
      float ww = expf(c0 * dist);
      wE[e] = ww;
      unsafeAtomicAdd(&deg[j], ww);
    }
  }
}

// ---------------- CSR build (edge list is a fixed input) ---------------------
__global__ __launch_bounds__(256)
void csrCountK(const int* __restrict__ ei, const int* __restrict__ ej,
               int* __restrict__ cntO, int* __restrict__ cntI)
{
  int e = blockIdx.x * 256 + threadIdx.x;
  atomicAdd(&cntO[ei[e]], 1);
  atomicAdd(&cntI[ej[e]], 1);
}

__global__ __launch_bounds__(256)
void csrScanK(const int* __restrict__ cntO, const int* __restrict__ cntI,
              int* __restrict__ ofsO, int* __restrict__ ofsI)
{
  __shared__ int smO[256], smI[256];
  int t = threadIdx.x;
  int lo[16], li[16];
  int sO = 0, sI = 0;
  #pragma unroll
  for (int k = 0; k < 16; k++) {
    lo[k] = cntO[t * 16 + k]; li[k] = cntI[t * 16 + k];
    sO += lo[k]; sI += li[k];
  }
  smO[t] = sO; smI[t] = sI;
  __syncthreads();
  for (int off = 1; off < 256; off <<= 1) {
    int aO = (t >= off) ? smO[t - off] : 0;
    int aI = (t >= off) ? smI[t - off] : 0;
    __syncthreads();
    smO[t] += aO; smI[t] += aI;
    __syncthreads();
  }
  int bO = smO[t] - sO;
  int bI = smI[t] - sI;
  #pragma unroll
  for (int k = 0; k < 16; k++) {
    ofsO[t * 16 + k] = bO; bO += lo[k];
    ofsI[t * 16 + k] = bI; bI += li[k];
  }
}

__global__ __launch_bounds__(256)
void csrFillK(const int* __restrict__ ei, const int* __restrict__ ej,
              const int* __restrict__ ofsO, const int* __restrict__ ofsI,
              int* __restrict__ curO, int* __restrict__ curI,
              int2* __restrict__ lstO, int2* __restrict__ lstI)
{
  int e = blockIdx.x * 256 + threadIdx.x;
  int i = ei[e], j = ej[e];
  int p = atomicAdd(&curO[i], 1); lstO[ofsO[i] + p] = make_int2(j, e);
  int q = atomicAdd(&curI[j], 1); lstI[ofsI[j] + q] = make_int2(i, e);
}

// ---------------- graph Laplacian gather, fused W² (wave per node) -----------
__global__ __launch_bounds__(256)
void gatherLapK(const int2* __restrict__ lstO, const int2* __restrict__ lstI,
                const int* __restrict__ ofsO, const int* __restrict__ ofsI,
                const int* __restrict__ cntO, const int* __restrict__ cntI,
                const float* __restrict__ wE, const float* __restrict__ deg,
                const ushort* __restrict__ fTh, ushort* __restrict__ lapTh)
{
  int w = threadIdx.x >> 6, lane = threadIdx.x & 63;
  int n = blockIdx.x * 4 + w;
  ushort4 u = ((const ushort4*)(fTh + (size_t)n * CF))[lane];
  float o0 = bf2f(u.x), o1 = bf2f(u.y), o2 = bf2f(u.z), o3 = bf2f(u.w);
  float dn = rsqrtf(1.0f + deg[n]);
  float a0 = 0, a1 = 0, a2 = 0, a3 = 0;
  int p0 = ofsO[n], pc = cntO[n];
  for (int k = 0; k < pc; k++) {
    int2 oe = lstO[p0 + k];
    float W = dn * wE[oe.y] * rsqrtf(1.0f + deg[oe.x]);
    float W2 = W * W;
    ushort4 v = ((const ushort4*)(fTh + (size_t)oe.x * CF))[lane];
    a0 += W2 * (o0 - bf2f(v.x)); a1 += W2 * (o1 - bf2f(v.y));
    a2 += W2 * (o2 - bf2f(v.z)); a3 += W2 * (o3 - bf2f(v.w));
  }
  int q0 = ofsI[n], qc = cntI[n];
  for (int k = 0; k < qc; k++) {
    int2 oe = lstI[q0 + k];
    float W = dn * wE[oe.y] * rsqrtf(1.0f + deg[oe.x]);
    float W2 = W * W;
    ushort4 v = ((const ushort4*)(fTh + (size_t)oe.x * CF))[lane];
    a0 += W2 * (o0 - bf2f(v.x)); a1 += W2 * (o1 - bf2f(v.y));
    a2 += W2 * (o2 - bf2f(v.z)); a3 += W2 * (o3 - bf2f(v.w));
  }
  ushort4 rv;
  rv.x = f2bf(a0); rv.y = f2bf(a1); rv.z = f2bf(a2); rv.w = f2bf(a3);
  ((ushort4*)(lapTh + (size_t)n * CF))[lane] = rv;
}

// ---------------- row log-softmax ----------------
__global__ __launch_bounds__(256)
void logSoftmaxK(const float* __restrict__ logits, float* __restrict__ out)
{
  int n = blockIdx.x;
  const float* row = logits + (size_t)n * NOUT;
  float mx = -1e30f;
  for (int o = threadIdx.x; o < NOUT; o += 256) mx = fmaxf(mx, row[o]);
  mx = blockMaxF(mx);
  float se = 0;
  for (int o = threadIdx.x; o < NOUT; o += 256) se += expf(row[o] - mx);
  se = blockSumF(se);
  float lse = mx + logf(se);
  for (int o = threadIdx.x; o < NOUT; o += 256) out[(size_t)n * NOUT + o] = row[o] - lse;
}

extern "C" void kernel_launch(void* const* d_in, const int* in_sizes, int n_in,
                              void* d_out, int out_size, void* d_ws, size_t ws_size,
                              hipStream_t stream)
{
  (void)in_sizes; (void)n_in; (void)out_size; (void)ws_size;
  const float* x0      = (const float*)d_in[0];
  const float* K1      = (const float*)d_in[1];
  const float* K2      = (const float*)d_in[2];
  const float* KNclose = (const float*)d_in[3];
  const float* KN1     = (const float*)d_in[4];
  const float* KN2     = (const float*)d_in[5];
  const float* lin1w   = (const float*)d_in[6];
  const float* lin1b   = (const float*)d_in[7];
  const float* lin2w   = (const float*)d_in[8];
  const float* lin2b   = (const float*)d_in[9];
  const int*   ei      = (const int*)d_in[10];
  const int*   ej      = (const int*)d_in[11];
  float* out = (float*)d_out;

  // ---------------- workspace layout ----------------
  float* base   = (float*)d_ws;
  float* fT     = base;                     // [N][CF] f32 residual features
  float* logits = fT + (size_t)CN;          // [N][NOUT]
  float* Gp     = logits + 4 * (size_t)CN;  // [16][256*256] Gram split-K partials
  float* sq     = Gp + (size_t)CN;          // [N]
  float* deg    = sq + N_NODES;             // [N]
  float* sP     = deg + N_NODES;            // [64][256]
  float* hP     = sP + 64 * 256;            // [64][256]
  float* wE     = hP + 64 * 256;            // [E0]
  double* pS    = (double*)(wE + E0_EDGES + 2);  // [512]
  double* pS2   = pS + 512;                 // [512]
  double* parts = pS2 + 512;                // [5*64]

  ushort* u0 = (ushort*)(((uintptr_t)(parts + 5 * STD_BLOCKS) + 15) & ~(uintptr_t)15);
  ushort* fTh   = u0;                       // [N][CF] bf16 features
  ushort* fh    = fTh + (size_t)CN;         // [CF][N] transposed bf16 (xt at open)
  ushort* lapTh = fh + (size_t)CN;          // lap bf16; x1 at close
  ushort* uTh   = lapTh + (size_t)CN;       // intermediate bf16; y at close
  ushort* wH    = uTh + (size_t)CN;         // all weights bf16
  int* ib = (int*)(((uintptr_t)(wH + NW_TOT) + 15) & ~(uintptr_t)15);
  int*  cntO = ib;
  int*  cntI = cntO + N_NODES;
  int*  ofsO = cntI + N_NODES;
  int*  ofsI = ofsO + N_NODES;
  int*  curO = ofsI + N_NODES;
  int*  curI = curO + N_NODES;
  int2* lstO = (int2*)(curI + N_NODES);
  int2* lstI = lstO + E0_EDGES;

  // ---- one-time: weight bf16 + CSR ----
  prepWK<<<dim3(64, 7), 256, 0, stream>>>(K1, K2, KNclose, KN1, KN2, lin1w, lin2w, wH);
  hipMemsetAsync(cntO, 0, 6 * N_NODES * sizeof(int), stream);
  csrCountK<<<E0_EDGES/256, 256, 0, stream>>>(ei, ej, cntO, cntI);
  csrScanK<<<1, 256, 0, stream>>>(cntO, cntI, ofsO, ofsI);
  csrFillK<<<E0_EDGES/256, 256, 0, stream>>>(ei, ej, ofsO, ofsI, curO, curI, lstO, lstI);

  // ---- opening: fT = tanh(LN(x0T·K1^T))·K2^T ----
  transposeBF<<<dim3(N_NODES/32, CIN/32), dim3(32, 8), 0, stream>>>(x0, fh, CIN, N_NODES);
  gemmB1<64,32,0,0,1,0,1,false><<<dim3(8,64,1), 256, 0, stream>>>(
      fh, fh, CIN, 1 << 30, wH + OFF_K1, CIN,
      nullptr, uTh, nullptr, CF, 0, CIN, 1.f, 0.f, nullptr, pS, pS2);
  tanhNormBF<<<256, 256, 0, stream>>>(uTh, pS, pS2);
  gemmB1<128,32,0,1,1,1,0,false><<<dim3(8,64,1), 256, 0, stream>>>(
      uTh, uTh, CF, 1 << 30, wH + OFF_K2, CF,
      fT, fTh, fh, CF, 0, CF, 1.f, 0.f, nullptr, nullptr, nullptr);

  for (int L = 0; L < NLAYER; L++) {
    const ushort* k1h = wH + OFF_KN1 + (size_t)L * CF * 2 * CF;
    const ushort* k2h = wH + OFF_KN2 + (size_t)L * CF * CF;

    sqSHK<<<64, 256, 0, stream>>>(fTh, sq, sP, hP, deg);
    // Gram upper-triangle tiles, split-K=16, plain per-z partial stores
    gemmB1<128,64,0,1,0,0,0,true><<<dim3(10,1,16), 256, 0, stream>>>(
        fh, fh, N_NODES, 1 << 30, fh, N_NODES,
        Gp, nullptr, nullptr, CF, 65536, 256, 1.f, 0.f, nullptr, nullptr, nullptr);
    stdPartsK<<<STD_BLOCKS, 256, 0, stream>>>(sP, hP, Gp, sq, parts);
    edgeWK<<<E0_EDGES/16, 256, 0, stream>>>(ei, ej, fTh, sq, parts, wE, deg);
    gatherLapK<<<N_NODES/4, 256, 0, stream>>>(lstO, lstI, ofsO, ofsI, cntO, cntI,
                                              wE, deg, fTh, lapTh);
    // uT = [fT, lapT]·KN1^T (fused K=512 dual-A) + LN-stat partials
    gemmB1<128,32,0,0,1,0,1,false><<<dim3(8,64,1), 256, 0, stream>>>(
        fTh, lapTh, CF, 256, k1h, 2*CF,
        nullptr, uTh, nullptr, CF, 0, 2*CF, 1.f, 0.f, nullptr, pS, pS2);
    tanhNormBF<<<256, 256, 0, stream>>>(uTh, pS, pS2);
    // fT += 0.1 · uT·KN2^T  (writes f32 fT, bf16 fTh, transposed bf16 fh)
    gemmB1<128,32,0,1,1,1,0,false><<<dim3(8,64,1), 256, 0, stream>>>(
        uTh, uTh, CF, 1 << 30, k2h, CF,
        fT, fTh, fh, CF, 0, CF, 0.1f, 1.f, nullptr, nullptr, nullptr);
  }

  // ---- close: y = fT·KNclose^T ; x1 = elu(y·lin1^T+b1) ; logits ; log_softmax ----
  gemmB1<128,32,0,0,1,0,0,false><<<dim3(8,64,1), 256, 0, stream>>>(
      fTh, fTh, CF, 1 << 30, wH + OFF_KNC, CF,
      nullptr, uTh, nullptr, CF, 0, CF, 1.f, 0.f, nullptr, nullptr, nullptr);
  gemmB1<128,32,1,0,1,0,0,false><<<dim3(8,64,1), 256, 0, stream>>>(
      uTh, uTh, CF, 1 << 30, wH + OFF_L1, CF,
      nullptr, lapTh, nullptr, CF, 0, CF, 1.f, 0.f, lin1b, nullptr, nullptr);
  gemmB1<128,64,0,1,0,0,0,false><<<dim3(16,64,1), 256, 0, stream>>>(
      lapTh, lapTh, CF, 1 << 30, wH + OFF_L2, CF,
      logits, nullptr, nullptr, NOUT, 0, CF, 1.f, 0.f, lin2b, nullptr, nullptr);
  logSoftmaxK<<<N_NODES, 256, 0, stream>>>(logits, out);
}

// Round 14
// 779.978 us; speedup vs baseline: 1.0346x; 1.0346x over previous
//
#include <hip/hip_runtime.h>
#include <hip/hip_bf16.h>

// Problem constants (fixed instance)
#define N_NODES 4096
#define CF      256
#define CIN     64
#define E0_EDGES 65536
#define NLAYER  8
#define NOUT    1024
#define CN      (CF * N_NODES)
#define STD_BLOCKS 64

typedef unsigned short ushort;
typedef __attribute__((ext_vector_type(8))) short s8v;   // 8 bf16
typedef __attribute__((ext_vector_type(4))) float f4v;   // MFMA acc

__device__ __forceinline__ ushort f2bf(float x){
  unsigned int u = __builtin_bit_cast(unsigned int, x);
  return (ushort)((u + 0x7FFFu + ((u >> 16) & 1u)) >> 16);
}
__device__ __forceinline__ float bf2f(ushort h){
  unsigned int u = ((unsigned int)h) << 16;
  return __builtin_bit_cast(float, u);
}

// ---------------- reduction helpers ----------------
__device__ __forceinline__ float waveSumF(float v){
  #pragma unroll
  for (int o = 32; o; o >>= 1) v += __shfl_xor(v, o);
  return v;
}
__device__ __forceinline__ double waveSumD(double v){
  #pragma unroll
  for (int o = 32; o; o >>= 1) v += __shfl_xor(v, o);
  return v;
}
__device__ __forceinline__ float waveMaxF(float v){
  #pragma unroll
  for (int o = 32; o; o >>= 1) v = fmaxf(v, __shfl_xor(v, o));
  return v;
}
__device__ float blockSumF(float v){
  __shared__ float sm[4];
  v = waveSumF(v);
  int l = threadIdx.x & 63, w = threadIdx.x >> 6;
  __syncthreads();
  if (l == 0) sm[w] = v;
  __syncthreads();
  return sm[0] + sm[1] + sm[2] + sm[3];
}
__device__ double blockSumD(double v){
  __shared__ double sm[4];
  v = waveSumD(v);
  int l = threadIdx.x & 63, w = threadIdx.x >> 6;
  __syncthreads();
  if (l == 0) sm[w] = v;
  __syncthreads();
  return sm[0] + sm[1] + sm[2] + sm[3];
}
__device__ float blockMaxF(float v){
  __shared__ float sm[4];
  v = waveMaxF(v);
  int l = threadIdx.x & 63, w = threadIdx.x >> 6;
  __syncthreads();
  if (l == 0) sm[w] = v;
  __syncthreads();
  return fmaxf(fmaxf(sm[0], sm[1]), fmaxf(sm[2], sm[3]));
}

// ---------------- bf16 MFMA GEMM, depth-2 prefetch, templated MTxNT ----------
// C[M,N] = alpha*A·B^T (+beta*Cf, +bias, act). A,B bf16 row-major K-contiguous.
// A rows split across A1/A2 at K=splitAt. Tile MTxNT; 4 waves as 2x2
// (wave-tile MT/2 x NT/2). 32x32 tile -> grid 8x128 = 1024 blocks -> 4
// blocks/CU co-resident (34.8KB LDS) -> deep cross-block latency hiding.
// Loads issued two tiles ahead (static ping-pong regs). One barrier per tile.
// WFH: extra transposed bf16 write. TRI: upper-triangle 64x64 tiles of 256².
// SQSH: blocks with z*gridDim.x+bx < 64 run the fused per-node sq + s/h
// partial + deg-zero prologue (own LDS arrays; Gram is 160 blocks on 256 CUs
// so the prologue is fully parallel slack).
// cStrideZ!=0: per-z split-K partials (plain store).
// NOTE (R9): do NOT fuse tanh into STORETILE (critical-path VALU, ~3x cost).
// NOTE (R10): L2-resident redundancy (per-block parts re-reduce) is free;
// serializing more work per wave is not.
#define MF(a,b,c) c = __builtin_amdgcn_mfma_f32_16x16x32_bf16(a, b, c, 0, 0, 0)

template<int BK, int MT, int NT, int ACT, bool WF32, bool WBF, bool WFH,
         bool MV, bool TRI, bool SQSH>
__global__ __launch_bounds__(256)
void gemmB1(const ushort* __restrict__ A1, const ushort* __restrict__ A2,
            int lda, int splitAt,
            const ushort* __restrict__ B, int ldb,
            float* __restrict__ Cf, ushort* __restrict__ Cb, ushort* __restrict__ Cfh,
            int ldc, size_t cStrideZ, int kChunk,
            float alpha, float beta, const float* __restrict__ bias,
            double* __restrict__ pS, double* __restrict__ pS2,
            const ushort* __restrict__ fThp, float* __restrict__ sqp,
            float* __restrict__ sPp, float* __restrict__ hPp,
            float* __restrict__ degp)
{
  constexpr int TPR_A = 256 / MT;                 // threads per A row
  constexpr int TPR_B = 256 / NT;
  constexpr int NCA = (MT * BK) / 2048;           // s8v chunks per thread
  constexpr int NCB = (NT * BK) / 2048;
  constexpr int MR = MT / 32, NR = NT / 32;       // frags per wave
  __shared__ ushort As[2][MT][BK + 8], Bs[2][NT][BK + 8];
  const int tid = threadIdx.x;
  const int ar = tid / TPR_A, ak = (tid % TPR_A) * (NCA * 8);
  const int br = tid / TPR_B, bk_ = (tid % TPR_B) * (NCB * 8);
  int bx = blockIdx.x, by = blockIdx.y;
  if (TRI) {
    const int trT[10] = {0,0,0,0,1,1,1,2,2,3};
    const int tcT[10] = {0,1,2,3,1,2,3,2,3,3};
    by = trT[blockIdx.x]; bx = tcT[blockIdx.x];
  }

  if constexpr (SQSH) {
    __shared__ float smS[4][256], smH[4][256];
    int g = blockIdx.z * gridDim.x + blockIdx.x;   // 16*10 = 160 blocks
    if (g < 64) {
      int w = tid >> 6, ln = tid & 63;
      if (tid < 64) degp[g * 64 + tid] = 0.0f;
      float sA[4] = {0,0,0,0}, hA[4] = {0,0,0,0};
      for (int rr = 0; rr < 16; rr++) {
        int n = g * 64 + rr * 4 + w;
        ushort4 u = ((const ushort4*)(fThp + (size_t)n * CF))[ln];
        float x0 = bf2f(u.x), x1 = bf2f(u.y), x2 = bf2f(u.z), x3 = bf2f(u.w);
        float q = waveSumF(x0*x0 + x1*x1 + x2*x2 + x3*x3);
        if (ln == 0) sqp[n] = q;
        sA[0] += x0; sA[1] += x1; sA[2] += x2; sA[3] += x3;
        hA[0] += x0*q; hA[1] += x1*q; hA[2] += x2*q; hA[3] += x3*q;
      }
      #pragma unroll
      for (int k = 0; k < 4; k++) { smS[w][ln*4+k] = sA[k]; smH[w][ln*4+k] = hA[k]; }
      __syncthreads();
      sPp[(size_t)g * 256 + tid] = smS[0][tid] + smS[1][tid] + smS[2][tid] + smS[3][tid];
      hPp[(size_t)g * 256 + tid] = smH[0][tid] + smH[1][tid] + smH[2][tid] + smH[3][tid];
    }
  }

  const int row0 = by * MT, col0 = bx * NT;
  const int kStart = blockIdx.z * kChunk;
  const int nT = kChunk / BK;

  const int wid = tid >> 6, lane = tid & 63;
  const int wr = (wid >> 1) * (MT / 2), wc = (wid & 1) * (NT / 2);
  const int fr = lane & 15, fk = (lane >> 4) * 8;

  f4v acc[MR][NR] = {};
  s8v rA0[NCA], rB0[NCB], rA1[NCA], rB1[NCB];

#define LOADTILE(T, RA, RB) { \
    int k0 = kStart + (T) * BK; \
    const ushort* Ag; int kk; \
    if (k0 < splitAt) { Ag = A1; kk = k0; } else { Ag = A2; kk = k0 - splitAt; } \
    size_t aoff = (size_t)(row0 + ar) * lda + kk + ak; \
    size_t boff = (size_t)(col0 + br) * ldb + k0 + bk_; \
    _Pragma("unroll") \
    for (int c = 0; c < NCA; c++) RA[c] = *(const s8v*)(Ag + aoff + 8 * c); \
    _Pragma("unroll") \
    for (int c = 0; c < NCB; c++) RB[c] = *(const s8v*)(B + boff + 8 * c); }

#define STORETILE(BUF, RA, RB) { \
    _Pragma("unroll") \
    for (int c = 0; c < NCA; c++) *(s8v*)&As[BUF][ar][ak + 8 * c] = RA[c]; \
    _Pragma("unroll") \
    for (int c = 0; c < NCB; c++) *(s8v*)&Bs[BUF][br][bk_ + 8 * c] = RB[c]; }

#define MFMAT(BUF) { \
    _Pragma("unroll") \
    for (int ks = 0; ks < BK; ks += 32) { \
      s8v a[MR], b[NR]; \
      _Pragma("unroll") \
      for (int m = 0; m < MR; m++) a[m] = *(const s8v*)&As[BUF][wr + m*16 + fr][ks + fk]; \
      _Pragma("unroll") \
      for (int n = 0; n < NR; n++) b[n] = *(const s8v*)&Bs[BUF][wc + n*16 + fr][ks + fk]; \
      _Pragma("unroll") \
      for (int m = 0; m < MR; m++) \
        _Pragma("unroll") \
        for (int n = 0; n < NR; n++) MF(a[m], b[n], acc[m][n]); } }

  LOADTILE(0, rA0, rB0);
  if (nT > 1) LOADTILE(1, rA1, rB1);
  STORETILE(0, rA0, rB0);

  for (int t = 0; t < nT; t += 2) {
    __syncthreads();                       // lds0(tile t) visible; old reads done
    if (t + 2 < nT) LOADTILE(t + 2, rA0, rB0);
    MFMAT(0);
    if (t + 1 < nT) {
      STORETILE(1, rA1, rB1);              // lds1 last read before top barrier
      __syncthreads();
      if (t + 3 < nT) LOADTILE(t + 3, rA1, rB1);
      MFMAT(1);
      if (t + 2 < nT) STORETILE(0, rA0, rB0);  // lds0 last read before mid barrier
    }
  }
#undef LOADTILE
#undef STORETILE
#undef MFMAT

  double s = 0, s2 = 0;
  #pragma unroll
  for (int m = 0; m < MR; m++)
    #pragma unroll
    for (int n = 0; n < NR; n++) {
      const int rowb = row0 + wr + m * 16 + (lane >> 4) * 4;
      const int col  = col0 + wc + n * 16 + fr;
      ushort4 hv;
      #pragma unroll
      for (int q = 0; q < 4; q++) {
        size_t cidx = (size_t)(rowb + q) * ldc + col;
        float v = alpha * acc[m][n][q];
        if (cStrideZ) {
          Cf[blockIdx.z * cStrideZ + cidx] = v;
        } else {
          if (beta != 0.0f) v += beta * Cf[cidx];
          if (bias) v += bias[col];
          if (ACT == 1) v = (v > 0.0f) ? v : expm1f(v);
          if (WF32) Cf[cidx] = v;
          if (WBF)  Cb[cidx] = f2bf(v);
          if (WFH)  ((ushort*)&hv)[q] = f2bf(v);
          if (MV)   { s += v; s2 += (double)v * v; }
        }
      }
      if (WFH && !cStrideZ)
        *(ushort4*)(Cfh + (size_t)col * N_NODES + rowb) = hv;
    }
  if (MV) {
    s  = blockSumD(s);
    s2 = blockSumD(s2);
    if (tid == 0) {
      int bid = blockIdx.y * gridDim.x + blockIdx.x;   // stats grids are <=1024 blocks
      pS[bid] = s; pS2[bid] = s2;
    }
  }
}

// ---------------- weight f32 -> bf16 (once per launch) ----------------------
#define OFF_K1   0
#define OFF_K2   16384
#define OFF_KNC  81920
#define OFF_KN1  147456
#define OFF_KN2  1196032
#define OFF_L1   1720320
#define OFF_L2   1785856
#define NW_TOT   2048000

__global__ __launch_bounds__(256)
void prepWK(const float* s0, const float* s1, const float* s2, const float* s3,
            const float* s4, const float* s5, const float* s6,
            ushort* __restrict__ h)
{
  const int sizes[7] = {16384, 65536, 65536, 1048576, 524288, 65536, 262144};
  const int offs[7]  = {OFF_K1, OFF_K2, OFF_KNC, OFF_KN1, OFF_KN2, OFF_L1, OFF_L2};
  int seg = blockIdx.y;
  const float* src = seg==0?s0: seg==1?s1: seg==2?s2: seg==3?s3: seg==4?s4: seg==5?s5: s6;
  int n = sizes[seg], off = offs[seg];
  for (int i = blockIdx.x * 256 + threadIdx.x; i < n; i += gridDim.x * 256)
    h[off + i] = f2bf(src[i]);
}

// ---------------- transpose f32 [R][Cc] -> bf16 [Cc][R] (open only) ----------
__global__ __launch_bounds__(256)
void transposeBF(const float* __restrict__ in, ushort* __restrict__ outh, int R, int Cc)
{
  __shared__ float t[32][33];
  int x  = blockIdx.x * 32 + threadIdx.x;
  int y0 = blockIdx.y * 32;
  for (int dy = threadIdx.y; dy < 32; dy += 8)
    t[dy][threadIdx.x] = in[(size_t)(y0 + dy) * Cc + x];
  __syncthreads();
  int ox  = y0 + threadIdx.x;
  int oy0 = blockIdx.x * 32;
  for (int dy = threadIdx.y; dy < 32; dy += 8)
    outh[(size_t)(oy0 + dy) * R + ox] = f2bf(t[threadIdx.x][dy]);
}

// ---------------- whole-tensor tanh-LN in place on bf16 ---------------------
// Stats partial arrays are 1024 entries (8x128 GEMM grids).
__global__ __launch_bounds__(256)
void tanhNormBF(ushort* __restrict__ h, const double* __restrict__ pS,
                const double* __restrict__ pS2)
{
  __shared__ float bc[2];
  double a = pS[threadIdx.x] + pS[threadIdx.x + 256] +
             pS[threadIdx.x + 512] + pS[threadIdx.x + 768];
  double b = pS2[threadIdx.x] + pS2[threadIdx.x + 256] +
             pS2[threadIdx.x + 512] + pS2[threadIdx.x + 768];
  a = blockSumD(a);
  b = blockSumD(b);
  if (threadIdx.x == 0) {
    double m   = a / (double)CN;
    double var = b / (double)CN - m * m;
    bc[0] = (float)m;
    bc[1] = (float)(1.0 / sqrt(var + 1e-5));
  }
  __syncthreads();
  float mf = bc[0], rs = bc[1];
  for (size_t i = ((size_t)blockIdx.x * 256 + threadIdx.x) * 8; i < CN;
       i += (size_t)256 * 256 * 8) {
    s8v hv = *(s8v*)(h + i);
    #pragma unroll
    for (int k = 0; k < 8; k++) {
      float x = bf2f((ushort)hv[k]);
      x = tanhf((x - mf) * rs);
      hv[k] = (short)f2bf(x);
    }
    *(s8v*)(h + i) = hv;
  }
}

// ---------------- std(D) closed form: 64-block partials (upper-tri Gp) -------
__global__ __launch_bounds__(256)
void stdPartsK(const float* __restrict__ sP, const float* __restrict__ hP,
               const float* __restrict__ Gp, const float* __restrict__ sq,
               double* __restrict__ parts)
{
  int b = blockIdx.x, t = threadIdx.x;
  double S1 = 0, S2 = 0, sd = 0, hd = 0, gf = 0;
  for (int i = b * 256 + t; i < N_NODES; i += STD_BLOCKS * 256) {
    double q = sq[i]; S1 += q; S2 += q * q;
  }
  if (b == 0) {
    float sv = 0, hv = 0;
    for (int p = 0; p < 64; p++) { sv += sP[p * 256 + t]; hv += hP[p * 256 + t]; }
    sd = (double)sv * sv; hd = (double)hv * sv;
  }
  for (int i = b * 256 + t; i < CF * CF; i += STD_BLOCKS * 256) {
    int r = i >> 8, c = i & 255;
    if (r > c) continue;               // only upper-triangle tiles were computed
    double g = 0;
    #pragma unroll 4
    for (int z = 0; z < 16; z++) g += Gp[(size_t)z * 65536 + i];
    gf += (r == c) ? g * g : 2.0 * g * g;
  }
  S1 = blockSumD(S1);
  S2 = blockSumD(S2);
  sd = blockSumD(sd);
  hd = blockSumD(hd);
  gf = blockSumD(gf);
  if (t == 0) {
    parts[0 * STD_BLOCKS + b] = S1;
    parts[1 * STD_BLOCKS + b] = S2;
    parts[2 * STD_BLOCKS + b] = sd;
    parts[3 * STD_BLOCKS + b] = hd;
    parts[4 * STD_BLOCKS + b] = gf;
  }
}

// ---------------- edge affinities + inline std finalize + deg atomics --------
// 4096 blocks, 4 edges per wave.
__global__ __launch_bounds__(256)
void edgeWK(const int* __restrict__ ei, const int* __restrict__ ej,
            const ushort* __restrict__ fTh, const float* __restrict__ sq,
            const double* __restrict__ parts, float* __restrict__ wE,
            float* __restrict__ deg)
{
  __shared__ float c0s;
  if (threadIdx.x < 64) {
    int l = threadIdx.x;
    double v0 = waveSumD(parts[0 * STD_BLOCKS + l]);
    double v1 = waveSumD(parts[1 * STD_BLOCKS + l]);
    double v2 = waveSumD(parts[2 * STD_BLOCKS + l]);
    double v3 = waveSumD(parts[3 * STD_BLOCKS + l]);
    double v4 = waveSumD(parts[4 * STD_BLOCKS + l]);
    if (l == 0) {
      double NN = (double)N_NODES;
      double sum1 = 2.0 * NN * v0 - 2.0 * v2;
      double sum2 = 2.0 * NN * v1 + 2.0 * v0 * v0 + 4.0 * v4 - 8.0 * v3;
      double n2 = NN * NN;
      double var = (sum2 - sum1 * sum1 / n2) / (n2 - 1.0);
      double sdev = sqrt(var > 0 ? var : 0);
      c0s = (float)(-2.0 / sdev);
    }
  }
  __syncthreads();
  float c0 = c0s;
  int w = threadIdx.x >> 6, lane = threadIdx.x & 63;
  int e0 = (blockIdx.x * 4 + w) * 4;
  for (int q = 0; q < 4; q++) {
    int e = e0 + q;
    int i = ei[e], j = ej[e];
    ushort4 ua = ((const ushort4*)(fTh + (size_t)i * CF))[lane];
    ushort4 ub = ((const ushort4*)(fTh + (size_t)j * CF))[lane];
    float d = waveSumF(bf2f(ua.x)*bf2f(ub.x) + bf2f(ua.y)*bf2f(ub.y) +
                       bf2f(ua.z)*bf2f(ub.z) + bf2f(ua.w)*bf2f(ub.w));
    if (lane == 0) {
      float dist = fmaxf(sq[i] + sq[j] - 2.0f * d, 0.0f);
      float ww = expf(c0 * dist);
      wE[e] = ww;
      unsafeAtomicAdd(&deg[j], ww);
    }
  }
}

// ---------------- CSR build (edge list is a fixed input) ---------------------
__global__ __launch_bounds__(256)
void csrCountK(const int* __restrict__ ei, const int* __restrict__ ej,
               int* __restrict__ cntO, int* __restrict__ cntI)
{
  int e = blockIdx.x * 256 + threadIdx.x;
  atomicAdd(&cntO[ei[e]], 1);
  atomicAdd(&cntI[ej[e]], 1);
}

__global__ __launch_bounds__(256)
void csrScanK(const int* __restrict__ cntO, const int* __restrict__ cntI,
              int* __restrict__ ofsO, int* __restrict__ ofsI)
{
  __shared__ int smO[256], smI[256];
  int t = threadIdx.x;
  int lo[16], li[16];
  int sO = 0, sI = 0;
  #pragma unroll
  for (int k = 0; k < 16; k++) {
    lo[k] = cntO[t * 16 + k]; li[k] = cntI[t * 16 + k];
    sO += lo[k]; sI += li[k];
  }
  smO[t] = sO; smI[t] = sI;
  __syncthreads();
  for (int off = 1; off < 256; off <<= 1) {
    int aO = (t >= off) ? smO[t - off] : 0;
    int aI = (t >= off) ? smI[t - off] : 0;
    __syncthreads();
    smO[t] += aO; smI[t] += aI;
    __syncthreads();
  }
  int bO = smO[t] - sO;
  int bI = smI[t] - sI;
  #pragma unroll
  for (int k = 0; k < 16; k++) {
    ofsO[t * 16 + k] = bO; bO += lo[k];
    ofsI[t * 16 + k] = bI; bI += li[k];
  }
}

__global__ __launch_bounds__(256)
void csrFillK(const int* __restrict__ ei, const int* __restrict__ ej,
              const int* __restrict__ ofsO, const int* __restrict__ ofsI,
              int* __restrict__ curO, int* __restrict__ curI,
              int2* __restrict__ lstO, int2* __restrict__ lstI)
{
  int e = blockIdx.x * 256 + threadIdx.x;
  int i = ei[e], j = ej[e];
  int p = atomicAdd(&curO[i], 1); lstO[ofsO[i] + p] = make_int2(j, e);
  int q = atomicAdd(&curI[j], 1); lstI[ofsI[j] + q] = make_int2(i, e);
}

// ---------------- graph Laplacian gather, fused W² (wave per node) -----------
__global__ __launch_bounds__(256)
void gatherLapK(const int2* __restrict__ lstO, const int2* __restrict__ lstI,
                const int* __restrict__ ofsO, const int* __restrict__ ofsI,
                const int* __restrict__ cntO, const int* __restrict__ cntI,
                const float* __restrict__ wE, const float* __restrict__ deg,
                const ushort* __restrict__ fTh, ushort* __restrict__ lapTh)
{
  int w = threadIdx.x >> 6, lane = threadIdx.x & 63;
  int n = blockIdx.x * 4 + w;
  ushort4 u = ((const ushort4*)(fTh + (size_t)n * CF))[lane];
  float o0 = bf2f(u.x), o1 = bf2f(u.y), o2 = bf2f(u.z), o3 = bf2f(u.w);
  float dn = rsqrtf(1.0f + deg[n]);
  float a0 = 0, a1 = 0, a2 = 0, a3 = 0;
  int p0 = ofsO[n], pc = cntO[n];
  for (int k = 0; k < pc; k++) {
    int2 oe = lstO[p0 + k];
    float W = dn * wE[oe.y] * rsqrtf(1.0f + deg[oe.x]);
    float W2 = W * W;
    ushort4 v = ((const ushort4*)(fTh + (size_t)oe.x * CF))[lane];
    a0 += W2 * (o0 - bf2f(v.x)); a1 += W2 * (o1 - bf2f(v.y));
    a2 += W2 * (o2 - bf2f(v.z)); a3 += W2 * (o3 - bf2f(v.w));
  }
  int q0 = ofsI[n], qc = cntI[n];
  for (int k = 0; k < qc; k++) {
    int2 oe = lstI[q0 + k];
    float W = dn * wE[oe.y] * rsqrtf(1.0f + deg[oe.x]);
    float W2 = W * W;
    ushort4 v = ((const ushort4*)(fTh + (size_t)oe.x * CF))[lane];
    a0 += W2 * (o0 - bf2f(v.x)); a1 += W2 * (o1 - bf2f(v.y));
    a2 += W2 * (o2 - bf2f(v.z)); a3 += W2 * (o3 - bf2f(v.w));
  }
  ushort4 rv;
  rv.x = f2bf(a0); rv.y = f2bf(a1); rv.z = f2bf(a2); rv.w = f2bf(a3);
  ((ushort4*)(lapTh + (size_t)n * CF))[lane] = rv;
}

// ---------------- row log-softmax ----------------
__global__ __launch_bounds__(256)
void logSoftmaxK(const float* __restrict__ logits, float* __restrict__ out)
{
  int n = blockIdx.x;
  const float* row = logits + (size_t)n * NOUT;
  float mx = -1e30f;
  for (int o = threadIdx.x; o < NOUT; o += 256) mx = fmaxf(mx, row[o]);
  mx = blockMaxF(mx);
  float se = 0;
  for (int o = threadIdx.x; o < NOUT; o += 256) se += expf(row[o] - mx);
  se = blockSumF(se);
  float lse = mx + logf(se);
  for (int o = threadIdx.x; o < NOUT; o += 256) out[(size_t)n * NOUT + o] = row[o] - lse;
}

extern "C" void kernel_launch(void* const* d_in, const int* in_sizes, int n_in,
                              void* d_out, int out_size, void* d_ws, size_t ws_size,
                              hipStream_t stream)
{
  (void)in_sizes; (void)n_in; (void)out_size; (void)ws_size;
  const float* x0      = (const float*)d_in[0];
  const float* K1      = (const float*)d_in[1];
  const float* K2      = (const float*)d_in[2];
  const float* KNclose = (const float*)d_in[3];
  const float* KN1     = (const float*)d_in[4];
  const float* KN2     = (const float*)d_in[5];
  const float* lin1w   = (const float*)d_in[6];
  const float* lin1b   = (const float*)d_in[7];
  const float* lin2w   = (const float*)d_in[8];
  const float* lin2b   = (const float*)d_in[9];
  const int*   ei      = (const int*)d_in[10];
  const int*   ej      = (const int*)d_in[11];
  float* out = (float*)d_out;

  // ---------------- workspace layout ----------------
  float* base   = (float*)d_ws;
  float* fT     = base;                     // [N][CF] f32 residual features
  float* logits = fT + (size_t)CN;          // [N][NOUT]
  float* Gp     = logits + 4 * (size_t)CN;  // [16][256*256] Gram split-K partials
  float* sq     = Gp + (size_t)CN;          // [N]
  float* deg    = sq + N_NODES;             // [N]
  float* sP     = deg + N_NODES;            // [64][256]
  float* hP     = sP + 64 * 256;            // [64][256]
  float* wE     = hP + 64 * 256;            // [E0]
  double* pS    = (double*)(wE + E0_EDGES + 2);  // [1024]
  double* pS2   = pS + 1024;                // [1024]
  double* parts = pS2 + 1024;               // [5*64]

  ushort* u0 = (ushort*)(((uintptr_t)(parts + 5 * STD_BLOCKS) + 15) & ~(uintptr_t)15);
  ushort* fTh   = u0;                       // [N][CF] bf16 features
  ushort* fh    = fTh + (size_t)CN;         // [CF][N] transposed bf16 (xt at open)
  ushort* lapTh = fh + (size_t)CN;          // lap bf16; x1 at close
  ushort* uTh   = lapTh + (size_t)CN;       // intermediate bf16; y at close
  ushort* wH    = uTh + (size_t)CN;         // all weights bf16
  int* ib = (int*)(((uintptr_t)(wH + NW_TOT) + 15) & ~(uintptr_t)15);
  int*  cntO = ib;
  int*  cntI = cntO + N_NODES;
  int*  ofsO = cntI + N_NODES;
  int*  ofsI = ofsO + N_NODES;
  int*  curO = ofsI + N_NODES;
  int*  curI = curO + N_NODES;
  int2* lstO = (int2*)(curI + N_NODES);
  int2* lstI = lstO + E0_EDGES;

  // ---- one-time: weight bf16 + CSR ----
  prepWK<<<dim3(64, 7), 256, 0, stream>>>(K1, K2, KNclose, KN1, KN2, lin1w, lin2w, wH);
  hipMemsetAsync(cntO, 0, 6 * N_NODES * sizeof(int), stream);
  csrCountK<<<E0_EDGES/256, 256, 0, stream>>>(ei, ej, cntO, cntI);
  csrScanK<<<1, 256, 0, stream>>>(cntO, cntI, ofsO, ofsI);
  csrFillK<<<E0_EDGES/256, 256, 0, stream>>>(ei, ej, ofsO, ofsI, curO, curI, lstO, lstI);

  // ---- opening: fT = tanh(LN(x0T·K1^T))·K2^T ----
  transposeBF<<<dim3(N_NODES/32, CIN/32), dim3(32, 8), 0, stream>>>(x0, fh, CIN, N_NODES);
  gemmB1<64,32,32,0,0,1,0,1,false,false><<<dim3(8,128,1), 256, 0, stream>>>(
      fh, fh, CIN, 1 << 30, wH + OFF_K1, CIN,
      nullptr, uTh, nullptr, CF, 0, CIN, 1.f, 0.f, nullptr, pS, pS2,
      nullptr, nullptr, nullptr, nullptr, nullptr);
  tanhNormBF<<<256, 256, 0, stream>>>(uTh, pS, pS2);
  gemmB1<128,32,32,0,1,1,1,0,false,false><<<dim3(8,128,1), 256, 0, stream>>>(
      uTh, uTh, CF, 1 << 30, wH + OFF_K2, CF,
      fT, fTh, fh, CF, 0, CF, 1.f, 0.f, nullptr, nullptr, nullptr,
      nullptr, nullptr, nullptr, nullptr, nullptr);

  for (int L = 0; L < NLAYER; L++) {
    const ushort* k1h = wH + OFF_KN1 + (size_t)L * CF * 2 * CF;
    const ushort* k2h = wH + OFF_KN2 + (size_t)L * CF * CF;

    // Gram upper-triangle tiles, split-K=16, plain per-z partial stores,
    // fused sqSH prologue on blocks z*10+bx < 64
    gemmB1<128,64,64,0,1,0,0,0,true,true><<<dim3(10,1,16), 256, 0, stream>>>(
        fh, fh, N_NODES, 1 << 30, fh, N_NODES,
        Gp, nullptr, nullptr, CF, 65536, 256, 1.f, 0.f, nullptr, nullptr, nullptr,
        fTh, sq, sP, hP, deg);
    stdPartsK<<<STD_BLOCKS, 256, 0, stream>>>(sP, hP, Gp, sq, parts);
    edgeWK<<<E0_EDGES/16, 256, 0, stream>>>(ei, ej, fTh, sq, parts, wE, deg);
    gatherLapK<<<N_NODES/4, 256, 0, stream>>>(lstO, lstI, ofsO, ofsI, cntO, cntI,
                                              wE, deg, fTh, lapTh);
    // uT = [fT, lapT]·KN1^T (fused K=512 dual-A) + LN-stat partials
    gemmB1<128,32,32,0,0,1,0,1,false,false><<<dim3(8,128,1), 256, 0, stream>>>(
        fTh, lapTh, CF, 256, k1h, 2*CF,
        nullptr, uTh, nullptr, CF, 0, 2*CF, 1.f, 0.f, nullptr, pS, pS2,
        nullptr, nullptr, nullptr, nullptr, nullptr);
    tanhNormBF<<<256, 256, 0, stream>>>(uTh, pS, pS2);
    // fT += 0.1 · uT·KN2^T  (writes f32 fT, bf16 fTh, transposed bf16 fh)
    gemmB1<128,32,32,0,1,1,1,0,false,false><<<dim3(8,128,1), 256, 0, stream>>>(
        uTh, uTh, CF, 1 << 30, k2h, CF,
        fT, fTh, fh, CF, 0, CF, 0.1f, 1.f, nullptr, nullptr, nullptr,
        nullptr, nullptr, nullptr, nullptr, nullptr);
  }

  // ---- close: y = fT·KNclose^T ; x1 = elu(y·lin1^T+b1) ; logits ; log_softmax ----
  gemmB1<128,32,32,0,0,1,0,0,false,false><<<dim3(8,128,1), 256, 0, stream>>>(
      fTh, fTh, CF, 1 << 30, wH + OFF_KNC, CF,
      nullptr, uTh, nullptr, CF, 0, CF, 1.f, 0.f, nullptr, nullptr, nullptr,
      nullptr, nullptr, nullptr, nullptr, nullptr);
  gemmB1<128,32,32,1,0,1,0,0,false,false><<<dim3(8,128,1), 256, 0, stream>>>(
      uTh, uTh, CF, 1 << 30, wH + OFF_L1, CF,
      nullptr, lapTh, nullptr, CF, 0, CF, 1.f, 0.f, lin1b, nullptr, nullptr,
      nullptr, nullptr, nullptr, nullptr, nullptr);
  gemmB1<128,64,64,0,1,0,0,0,false,false><<<dim3(16,64,1), 256, 0, stream>>>(
      lapTh, lapTh, CF, 1 << 30, wH + OFF_L2, CF,
      logits, nullptr, nullptr, NOUT, 0, CF, 1.f, 0.f, lin2b, nullptr, nullptr,
      nullptr, nullptr, nullptr, nullptr, nullptr);
  logSoftmaxK<<<N_NODES, 256, 0, stream>>>(logits, out);
}

// Round 15
// 775.445 us; speedup vs baseline: 1.0407x; 1.0058x over previous
//
#include <hip/hip_runtime.h>
#include <hip/hip_bf16.h>

// Problem constants (fixed instance)
#define N_NODES 4096
#define CF      256
#define CIN     64
#define E0_EDGES 65536
#define NLAYER  8
#define NOUT    1024
#define CN      (CF * N_NODES)
#define STD_BLOCKS 64

typedef unsigned short ushort;
typedef __attribute__((ext_vector_type(8))) short s8v;   // 8 bf16
typedef __attribute__((ext_vector_type(4))) float f4v;   // MFMA acc

__device__ __forceinline__ ushort f2bf(float x){
  unsigned int u = __builtin_bit_cast(unsigned int, x);
  return (ushort)((u + 0x7FFFu + ((u >> 16) & 1u)) >> 16);
}
__device__ __forceinline__ float bf2f(ushort h){
  unsigned int u = ((unsigned int)h) << 16;
  return __builtin_bit_cast(float, u);
}

// ---------------- reduction helpers ----------------
__device__ __forceinline__ float waveSumF(float v){
  #pragma unroll
  for (int o = 32; o; o >>= 1) v += __shfl_xor(v, o);
  return v;
}
__device__ __forceinline__ double waveSumD(double v){
  #pragma unroll
  for (int o = 32; o; o >>= 1) v += __shfl_xor(v, o);
  return v;
}
__device__ __forceinline__ float waveMaxF(float v){
  #pragma unroll
  for (int o = 32; o; o >>= 1) v = fmaxf(v, __shfl_xor(v, o));
  return v;
}
__device__ float blockSumF(float v){
  __shared__ float sm[4];
  v = waveSumF(v);
  int l = threadIdx.x & 63, w = threadIdx.x >> 6;
  __syncthreads();
  if (l == 0) sm[w] = v;
  __syncthreads();
  return sm[0] + sm[1] + sm[2] + sm[3];
}
__device__ double blockSumD(double v){
  __shared__ double sm[4];
  v = waveSumD(v);
  int l = threadIdx.x & 63, w = threadIdx.x >> 6;
  __syncthreads();
  if (l == 0) sm[w] = v;
  __syncthreads();
  return sm[0] + sm[1] + sm[2] + sm[3];
}
__device__ float blockMaxF(float v){
  __shared__ float sm[4];
  v = waveMaxF(v);
  int l = threadIdx.x & 63, w = threadIdx.x >> 6;
  __syncthreads();
  if (l == 0) sm[w] = v;
  __syncthreads();
  return fmaxf(fmaxf(sm[0], sm[1]), fmaxf(sm[2], sm[3]));
}

// ---------------- bf16 MFMA GEMM, depth-2 prefetch, templated MT/NT/BK -------
// C[M,N] = alpha*A·B^T (+beta*Cf, +bias, act). A,B bf16 row-major K-contiguous.
// A rows split across A1/A2 at K=splitAt. Tile MTxNT; 4 waves as 2x2
// (wave-tile MT/2 x NT/2). 32x32/BK=64 -> 18.4KB LDS -> 8 blocks/CU (32
// waves/CU = HW max) -> deepest cross-block latency hiding.
// Loads issued two tiles ahead (static ping-pong regs). One barrier per tile.
// WFH: extra transposed bf16 write. TRI: upper-triangle 64x64 tiles of 256².
// SQSH: blocks with z*gridDim.x+bx < 64 run the fused per-node sq + s/h
// partial + deg-zero prologue (Gram is 160 blocks on 256 CUs -> free slack).
// cStrideZ!=0: per-z split-K partials (plain store).
// NOTE (R9): do NOT fuse tanh into STORETILE (critical-path VALU, ~3x cost).
// NOTE (R10): L2-resident redundancy (per-block parts re-reduce) is free;
// serializing more work per wave is not.
// NOTE (R13-R15): occupancy is the dominant lever for these latency-bound
// small GEMMs: 1->2->4->8 blocks/CU paid monotonically.
#define MF(a,b,c) c = __builtin_amdgcn_mfma_f32_16x16x32_bf16(a, b, c, 0, 0, 0)

template<int BK, int MT, int NT, int ACT, bool WF32, bool WBF, bool WFH,
         bool MV, bool TRI, bool SQSH>
__global__ __launch_bounds__(256)
void gemmB1(const ushort* __restrict__ A1, const ushort* __restrict__ A2,
            int lda, int splitAt,
            const ushort* __restrict__ B, int ldb,
            float* __restrict__ Cf, ushort* __restrict__ Cb, ushort* __restrict__ Cfh,
            int ldc, size_t cStrideZ, int kChunk,
            float alpha, float beta, const float* __restrict__ bias,
            double* __restrict__ pS, double* __restrict__ pS2,
            const ushort* __restrict__ fThp, float* __restrict__ sqp,
            float* __restrict__ sPp, float* __restrict__ hPp,
            float* __restrict__ degp)
{
  constexpr int TPR_A = 256 / MT;                 // threads per A row
  constexpr int TPR_B = 256 / NT;
  constexpr int NCA = (MT * BK) / 2048;           // s8v chunks per thread
  constexpr int NCB = (NT * BK) / 2048;
  constexpr int MR = MT / 32, NR = NT / 32;       // frags per wave
  __shared__ ushort As[2][MT][BK + 8], Bs[2][NT][BK + 8];
  const int tid = threadIdx.x;
  const int ar = tid / TPR_A, ak = (tid % TPR_A) * (NCA * 8);
  const int br = tid / TPR_B, bk_ = (tid % TPR_B) * (NCB * 8);
  int bx = blockIdx.x, by = blockIdx.y;
  if (TRI) {
    const int trT[10] = {0,0,0,0,1,1,1,2,2,3};
    const int tcT[10] = {0,1,2,3,1,2,3,2,3,3};
    by = trT[blockIdx.x]; bx = tcT[blockIdx.x];
  }

  if constexpr (SQSH) {
    __shared__ float smS[4][256], smH[4][256];
    int g = blockIdx.z * gridDim.x + blockIdx.x;   // 16*10 = 160 blocks
    if (g < 64) {
      int w = tid >> 6, ln = tid & 63;
      if (tid < 64) degp[g * 64 + tid] = 0.0f;
      float sA[4] = {0,0,0,0}, hA[4] = {0,0,0,0};
      for (int rr = 0; rr < 16; rr++) {
        int n = g * 64 + rr * 4 + w;
        ushort4 u = ((const ushort4*)(fThp + (size_t)n * CF))[ln];
        float x0 = bf2f(u.x), x1 = bf2f(u.y), x2 = bf2f(u.z), x3 = bf2f(u.w);
        float q = waveSumF(x0*x0 + x1*x1 + x2*x2 + x3*x3);
        if (ln == 0) sqp[n] = q;
        sA[0] += x0; sA[1] += x1; sA[2] += x2; sA[3] += x3;
        hA[0] += x0*q; hA[1] += x1*q; hA[2] += x2*q; hA[3] += x3*q;
      }
      #pragma unroll
      for (int k = 0; k < 4; k++) { smS[w][ln*4+k] = sA[k]; smH[w][ln*4+k] = hA[k]; }
      __syncthreads();
      sPp[(size_t)g * 256 + tid] = smS[0][tid] + smS[1][tid] + smS[2][tid] + smS[3][tid];
      hPp[(size_t)g * 256 + tid] = smH[0][tid] + smH[1][tid] + smH[2][tid] + smH[3][tid];
    }
  }

  const int row0 = by * MT, col0 = bx * NT;
  const int kStart = blockIdx.z * kChunk;
  const int nT = kChunk / BK;

  const int wid = tid >> 6, lane = tid & 63;
  const int wr = (wid >> 1) * (MT / 2), wc = (wid & 1) * (NT / 2);
  const int fr = lane & 15, fk = (lane >> 4) * 8;

  f4v acc[MR][NR] = {};
  s8v rA0[NCA], rB0[NCB], rA1[NCA], rB1[NCB];

#define LOADTILE(T, RA, RB) { \
    int k0 = kStart + (T) * BK; \
    const ushort* Ag; int kk; \
    if (k0 < splitAt) { Ag = A1; kk = k0; } else { Ag = A2; kk = k0 - splitAt; } \
    size_t aoff = (size_t)(row0 + ar) * lda + kk + ak; \
    size_t boff = (size_t)(col0 + br) * ldb + k0 + bk_; \
    _Pragma("unroll") \
    for (int c = 0; c < NCA; c++) RA[c] = *(const s8v*)(Ag + aoff + 8 * c); \
    _Pragma("unroll") \
    for (int c = 0; c < NCB; c++) RB[c] = *(const s8v*)(B + boff + 8 * c); }

#define STORETILE(BUF, RA, RB) { \
    _Pragma("unroll") \
    for (int c = 0; c < NCA; c++) *(s8v*)&As[BUF][ar][ak + 8 * c] = RA[c]; \
    _Pragma("unroll") \
    for (int c = 0; c < NCB; c++) *(s8v*)&Bs[BUF][br][bk_ + 8 * c] = RB[c]; }

#define MFMAT(BUF) { \
    _Pragma("unroll") \
    for (int ks = 0; ks < BK; ks += 32) { \
      s8v a[MR], b[NR]; \
      _Pragma("unroll") \
      for (int m = 0; m < MR; m++) a[m] = *(const s8v*)&As[BUF][wr + m*16 + fr][ks + fk]; \
      _Pragma("unroll") \
      for (int n = 0; n < NR; n++) b[n] = *(const s8v*)&Bs[BUF][wc + n*16 + fr][ks + fk]; \
      _Pragma("unroll") \
      for (int m = 0; m < MR; m++) \
        _Pragma("unroll") \
        for (int n = 0; n < NR; n++) MF(a[m], b[n], acc[m][n]); } }

  LOADTILE(0, rA0, rB0);
  if (nT > 1) LOADTILE(1, rA1, rB1);
  STORETILE(0, rA0, rB0);

  for (int t = 0; t < nT; t += 2) {
    __syncthreads();                       // lds0(tile t) visible; old reads done
    if (t + 2 < nT) LOADTILE(t + 2, rA0, rB0);
    MFMAT(0);
    if (t + 1 < nT) {
      STORETILE(1, rA1, rB1);              // lds1 last read before top barrier
      __syncthreads();
      if (t + 3 < nT) LOADTILE(t + 3, rA1, rB1);
      MFMAT(1);
      if (t + 2 < nT) STORETILE(0, rA0, rB0);  // lds0 last read before mid barrier
    }
  }
#undef LOADTILE
#undef STORETILE
#undef MFMAT

  double s = 0, s2 = 0;
  #pragma unroll
  for (int m = 0; m < MR; m++)
    #pragma unroll
    for (int n = 0; n < NR; n++) {
      const int rowb = row0 + wr + m * 16 + (lane >> 4) * 4;
      const int col  = col0 + wc + n * 16 + fr;
      ushort4 hv;
      #pragma unroll
      for (int q = 0; q < 4; q++) {
        size_t cidx = (size_t)(rowb + q) * ldc + col;
        float v = alpha * acc[m][n][q];
        if (cStrideZ) {
          Cf[blockIdx.z * cStrideZ + cidx] = v;
        } else {
          if (beta != 0.0f) v += beta * Cf[cidx];
          if (bias) v += bias[col];
          if (ACT == 1) v = (v > 0.0f) ? v : expm1f(v);
          if (WF32) Cf[cidx] = v;
          if (WBF)  Cb[cidx] = f2bf(v);
          if (WFH)  ((ushort*)&hv)[q] = f2bf(v);
          if (MV)   { s += v; s2 += (double)v * v; }
        }
      }
      if (WFH && !cStrideZ)
        *(ushort4*)(Cfh + (size_t)col * N_NODES + rowb) = hv;
    }
  if (MV) {
    s  = blockSumD(s);
    s2 = blockSumD(s2);
    if (tid == 0) {
      int bid = blockIdx.y * gridDim.x + blockIdx.x;   // stats grids are <=1024 blocks
      pS[bid] = s; pS2[bid] = s2;
    }
  }
}

// ---------------- weight f32 -> bf16 (once per launch) ----------------------
#define OFF_K1   0
#define OFF_K2   16384
#define OFF_KNC  81920
#define OFF_KN1  147456
#define OFF_KN2  1196032
#define OFF_L1   1720320
#define OFF_L2   1785856
#define NW_TOT   2048000

__global__ __launch_bounds__(256)
void prepWK(const float* s0, const float* s1, const float* s2, const float* s3,
            const float* s4, const float* s5, const float* s6,
            ushort* __restrict__ h)
{
  const int sizes[7] = {16384, 65536, 65536, 1048576, 524288, 65536, 262144};
  const int offs[7]  = {OFF_K1, OFF_K2, OFF_KNC, OFF_KN1, OFF_KN2, OFF_L1, OFF_L2};
  int seg = blockIdx.y;
  const float* src = seg==0?s0: seg==1?s1: seg==2?s2: seg==3?s3: seg==4?s4: seg==5?s5: s6;
  int n = sizes[seg], off = offs[seg];
  for (int i = blockIdx.x * 256 + threadIdx.x; i < n; i += gridDim.x * 256)
    h[off + i] = f2bf(src[i]);
}

// ---------------- transpose f32 [R][Cc] -> bf16 [Cc][R] (open only) ----------
__global__ __launch_bounds__(256)
void transposeBF(const float* __restrict__ in, ushort* __restrict__ outh, int R, int Cc)
{
  __shared__ float t[32][33];
  int x  = blockIdx.x * 32 + threadIdx.x;
  int y0 = blockIdx.y * 32;
  for (int dy = threadIdx.y; dy < 32; dy += 8)
    t[dy][threadIdx.x] = in[(size_t)(y0 + dy) * Cc + x];
  __syncthreads();
  int ox  = y0 + threadIdx.x;
  int oy0 = blockIdx.x * 32;
  for (int dy = threadIdx.y; dy < 32; dy += 8)
    outh[(size_t)(oy0 + dy) * R + ox] = f2bf(t[threadIdx.x][dy]);
}

// ---------------- whole-tensor tanh-LN in place on bf16 ---------------------
// Stats partial arrays are 1024 entries (8x128 GEMM grids).
__global__ __launch_bounds__(256)
void tanhNormBF(ushort* __restrict__ h, const double* __restrict__ pS,
                const double* __restrict__ pS2)
{
  __shared__ float bc[2];
  double a = pS[threadIdx.x] + pS[threadIdx.x + 256] +
             pS[threadIdx.x + 512] + pS[threadIdx.x + 768];
  double b = pS2[threadIdx.x] + pS2[threadIdx.x + 256] +
             pS2[threadIdx.x + 512] + pS2[threadIdx.x + 768];
  a = blockSumD(a);
  b = blockSumD(b);
  if (threadIdx.x == 0) {
    double m   = a / (double)CN;
    double var = b / (double)CN - m * m;
    bc[0] = (float)m;
    bc[1] = (float)(1.0 / sqrt(var + 1e-5));
  }
  __syncthreads();
  float mf = bc[0], rs = bc[1];
  for (size_t i = ((size_t)blockIdx.x * 256 + threadIdx.x) * 8; i < CN;
       i += (size_t)256 * 256 * 8) {
    s8v hv = *(s8v*)(h + i);
    #pragma unroll
    for (int k = 0; k < 8; k++) {
      float x = bf2f((ushort)hv[k]);
      x = tanhf((x - mf) * rs);
      hv[k] = (short)f2bf(x);
    }
    *(s8v*)(h + i) = hv;
  }
}

// ---------------- std(D) closed form: 64-block partials (upper-tri Gp) -------
__global__ __launch_bounds__(256)
void stdPartsK(const float* __restrict__ sP, const float* __restrict__ hP,
               const float* __restrict__ Gp, const float* __restrict__ sq,
               double* __restrict__ parts)
{
  int b = blockIdx.x, t = threadIdx.x;
  double S1 = 0, S2 = 0, sd = 0, hd = 0, gf = 0;
  for (int i = b * 256 + t; i < N_NODES; i += STD_BLOCKS * 256) {
    double q = sq[i]; S1 += q; S2 += q * q;
  }
  if (b == 0) {
    float sv = 0, hv = 0;
    for (int p = 0; p < 64; p++) { sv += sP[p * 256 + t]; hv += hP[p * 256 + t]; }
    sd = (double)sv * sv; hd = (double)hv * sv;
  }
  for (int i = b * 256 + t; i < CF * CF; i += STD_BLOCKS * 256) {
    int r = i >> 8, c = i & 255;
    if (r > c) continue;               // only upper-triangle tiles were computed
    double g = 0;
    #pragma unroll 4
    for (int z = 0; z < 16; z++) g += Gp[(size_t)z * 65536 + i];
    gf += (r == c) ? g * g : 2.0 * g * g;
  }
  S1 = blockSumD(S1);
  S2 = blockSumD(S2);
  sd = blockSumD(sd);
  hd = blockSumD(hd);
  gf = blockSumD(gf);
  if (t == 0) {
    parts[0 * STD_BLOCKS + b] = S1;
    parts[1 * STD_BLOCKS + b] = S2;
    parts[2 * STD_BLOCKS + b] = sd;
    parts[3 * STD_BLOCKS + b] = hd;
    parts[4 * STD_BLOCKS + b] = gf;
  }
}

// ---------------- edge affinities + inline std finalize + deg atomics --------
// 4096 blocks, 4 edges per wave.
__global__ __launch_bounds__(256)
void edgeWK(const int* __restrict__ ei, const int* __restrict__ ej,
            const ushort* __restrict__ fTh, const float* __restrict__ sq,
            const double* __restrict__ parts, float* __restrict__ wE,
            float* __restrict__ deg)
{
  __shared__ float c0s;
  if (threadIdx.x < 64) {
    int l = threadIdx.x;
    double v0 = waveSumD(parts[0 * STD_BLOCKS + l]);
    double v1 = waveSumD(parts[1 * STD_BLOCKS + l]);
    double v2 = waveSumD(parts[2 * STD_BLOCKS + l]);
    double v3 = waveSumD(parts[3 * STD_BLOCKS + l]);
    double v4 = waveSumD(parts[4 * STD_BLOCKS + l]);
    if (l == 0) {
      double NN = (double)N_NODES;
      double sum1 = 2.0 * NN * v0 - 2.0 * v2;
      double sum2 = 2.0 * NN * v1 + 2.0 * v0 * v0 + 4.0 * v4 - 8.0 * v3;
      double n2 = NN * NN;
      double var = (sum2 - sum1 * sum1 / n2) / (n2 - 1.0);
      double sdev = sqrt(var > 0 ? var : 0);
      c0s = (float)(-2.0 / sdev);
    }
  }
  __syncthreads();
  float c0 = c0s;
  int w = threadIdx.x >> 6, lane = threadIdx.x & 63;
  int e0 = (blockIdx.x * 4 + w) * 4;
  for (int q = 0; q < 4; q++) {
    int e = e0 + q;
    int i = ei[e], j = ej[e];
    ushort4 ua = ((const ushort4*)(fTh + (size_t)i * CF))[lane];
    ushort4 ub = ((const ushort4*)(fTh + (size_t)j * CF))[lane];
    float d = waveSumF(bf2f(ua.x)*bf2f(ub.x) + bf2f(ua.y)*bf2f(ub.y) +
                       bf2f(ua.z)*bf2f(ub.z) + bf2f(ua.w)*bf2f(ub.w));
    if (lane == 0) {
      float dist = fmaxf(sq[i] + sq[j] - 2.0f * d, 0.0f);
      float ww = expf(c0 * dist);
      wE[e] = ww;
      unsafeAtomicAdd(&deg[j], ww);
    }
  }
}

// ---------------- CSR build (edge list is a fixed input) ---------------------
__global__ __launch_bounds__(256)
void csrCountK(const int* __restrict__ ei, const int* __restrict__ ej,
               int* __restrict__ cntO, int* __restrict__ cntI)
{
  int e = blockIdx.x * 256 + threadIdx.x;
  atomicAdd(&cntO[ei[e]], 1);
  atomicAdd(&cntI[ej[e]], 1);
}

__global__ __launch_bounds__(256)
void csrScanK(const int* __restrict__ cntO, const int* __restrict__ cntI,
              int* __restrict__ ofsO, int* __restrict__ ofsI)
{
  __shared__ int smO[256], smI[256];
  int t = threadIdx.x;
  int lo[16], li[16];
  int sO = 0, sI = 0;
  #pragma unroll
  for (int k = 0; k < 16; k++) {
    lo[k] = cntO[t * 16 + k]; li[k] = cntI[t * 16 + k];
    sO += lo[k]; sI += li[k];
  }
  smO[t] = sO; smI[t] = sI;
  __syncthreads();
  for (int off = 1; off < 256; off <<= 1) {
    int aO = (t >= off) ? smO[t - off] : 0;
    int aI = (t >= off) ? smI[t - off] : 0;
    __syncthreads();
    smO[t] += aO; smI[t] += aI;
    __syncthreads();
  }
  int bO = smO[t] - sO;
  int bI = smI[t] - sI;
  #pragma unroll
  for (int k = 0; k < 16; k++) {
    ofsO[t * 16 + k] = bO; bO += lo[k];
    ofsI[t * 16 + k] = bI; bI += li[k];
  }
}

__global__ __launch_bounds__(256)
void csrFillK(const int* __restrict__ ei, const int* __restrict__ ej,
              const int* __restrict__ ofsO, const int* __restrict__ ofsI,
              int* __restrict__ curO, int* __restrict__ curI,
              int2* __restrict__ lstO, int2* __restrict__ lstI)
{
  int e = blockIdx.x * 256 + threadIdx.x;
  int i = ei[e], j = ej[e];
  int p = atomicAdd(&curO[i], 1); lstO[ofsO[i] + p] = make_int2(j, e);
  int q = atomicAdd(&curI[j], 1); lstI[ofsI[j] + q] = make_int2(i, e);
}

// ---------------- graph Laplacian gather, fused W² (wave per node) -----------
__global__ __launch_bounds__(256)
void gatherLapK(const int2* __restrict__ lstO, const int2* __restrict__ lstI,
                const int* __restrict__ ofsO, const int* __restrict__ ofsI,
                const int* __restrict__ cntO, const int* __restrict__ cntI,
                const float* __restrict__ wE, const float* __restrict__ deg,
                const ushort* __restrict__ fTh, ushort* __restrict__ lapTh)
{
  int w = threadIdx.x >> 6, lane = threadIdx.x & 63;
  int n = blockIdx.x * 4 + w;
  ushort4 u = ((const ushort4*)(fTh + (size_t)n * CF))[lane];
  float o0 = bf2f(u.x), o1 = bf2f(u.y), o2 = bf2f(u.z), o3 = bf2f(u.w);
  float dn = rsqrtf(1.0f + deg[n]);
  float a0 = 0, a1 = 0, a2 = 0, a3 = 0;
  int p0 = ofsO[n], pc = cntO[n];
  for (int k = 0; k < pc; k++) {
    int2 oe = lstO[p0 + k];
    float W = dn * wE[oe.y] * rsqrtf(1.0f + deg[oe.x]);
    float W2 = W * W;
    ushort4 v = ((const ushort4*)(fTh + (size_t)oe.x * CF))[lane];
    a0 += W2 * (o0 - bf2f(v.x)); a1 += W2 * (o1 - bf2f(v.y));
    a2 += W2 * (o2 - bf2f(v.z)); a3 += W2 * (o3 - bf2f(v.w));
  }
  int q0 = ofsI[n], qc = cntI[n];
  for (int k = 0; k < qc; k++) {
    int2 oe = lstI[q0 + k];
    float W = dn * wE[oe.y] * rsqrtf(1.0f + deg[oe.x]);
    float W2 = W * W;
    ushort4 v = ((const ushort4*)(fTh + (size_t)oe.x * CF))[lane];
    a0 += W2 * (o0 - bf2f(v.x)); a1 += W2 * (o1 - bf2f(v.y));
    a2 += W2 * (o2 - bf2f(v.z)); a3 += W2 * (o3 - bf2f(v.w));
  }
  ushort4 rv;
  rv.x = f2bf(a0); rv.y = f2bf(a1); rv.z = f2bf(a2); rv.w = f2bf(a3);
  ((ushort4*)(lapTh + (size_t)n * CF))[lane] = rv;
}

// ---------------- row log-softmax ----------------
__global__ __launch_bounds__(256)
void logSoftmaxK(const float* __restrict__ logits, float* __restrict__ out)
{
  int n = blockIdx.x;
  const float* row = logits + (size_t)n * NOUT;
  float mx = -1e30f;
  for (int o = threadIdx.x; o < NOUT; o += 256) mx = fmaxf(mx, row[o]);
  mx = blockMaxF(mx);
  float se = 0;
  for (int o = threadIdx.x; o < NOUT; o += 256) se += expf(row[o] - mx);
  se = blockSumF(se);
  float lse = mx + logf(se);
  for (int o = threadIdx.x; o < NOUT; o += 256) out[(size_t)n * NOUT + o] = row[o] - lse;
}

extern "C" void kernel_launch(void* const* d_in, const int* in_sizes, int n_in,
                              void* d_out, int out_size, void* d_ws, size_t ws_size,
                              hipStream_t stream)
{
  (void)in_sizes; (void)n_in; (void)out_size; (void)ws_size;
  const float* x0      = (const float*)d_in[0];
  const float* K1      = (const float*)d_in[1];
  const float* K2      = (const float*)d_in[2];
  const float* KNclose = (const float*)d_in[3];
  const float* KN1     = (const float*)d_in[4];
  const float* KN2     = (const float*)d_in[5];
  const float* lin1w   = (const float*)d_in[6];
  const float* lin1b   = (const float*)d_in[7];
  const float* lin2w   = (const float*)d_in[8];
  const float* lin2b   = (const float*)d_in[9];
  const int*   ei      = (const int*)d_in[10];
  const int*   ej      = (const int*)d_in[11];
  float* out = (float*)d_out;

  // ---------------- workspace layout ----------------
  float* base   = (float*)d_ws;
  float* fT     = base;                     // [N][CF] f32 residual features
  float* logits = fT + (size_t)CN;          // [N][NOUT]
  float* Gp     = logits + 4 * (size_t)CN;  // [16][256*256] Gram split-K partials
  float* sq     = Gp + (size_t)CN;          // [N]
  float* deg    = sq + N_NODES;             // [N]
  float* sP     = deg + N_NODES;            // [64][256]
  float* hP     = sP + 64 * 256;            // [64][256]
  float* wE     = hP + 64 * 256;            // [E0]
  double* pS    = (double*)(wE + E0_EDGES + 2);  // [1024]
  double* pS2   = pS + 1024;                // [1024]
  double* parts = pS2 + 1024;               // [5*64]

  ushort* u0 = (ushort*)(((uintptr_t)(parts + 5 * STD_BLOCKS) + 15) & ~(uintptr_t)15);
  ushort* fTh   = u0;                       // [N][CF] bf16 features
  ushort* fh    = fTh + (size_t)CN;         // [CF][N] transposed bf16 (xt at open)
  ushort* lapTh = fh + (size_t)CN;          // lap bf16; x1 at close
  ushort* uTh   = lapTh + (size_t)CN;       // intermediate bf16; y at close
  ushort* wH    = uTh + (size_t)CN;         // all weights bf16
  int* ib = (int*)(((uintptr_t)(wH + NW_TOT) + 15) & ~(uintptr_t)15);
  int*  cntO = ib;
  int*  cntI = cntO + N_NODES;
  int*  ofsO = cntI + N_NODES;
  int*  ofsI = ofsO + N_NODES;
  int*  curO = ofsI + N_NODES;
  int*  curI = curO + N_NODES;
  int2* lstO = (int2*)(curI + N_NODES);
  int2* lstI = lstO + E0_EDGES;

  // ---- one-time: weight bf16 + CSR ----
  prepWK<<<dim3(64, 7), 256, 0, stream>>>(K1, K2, KNclose, KN1, KN2, lin1w, lin2w, wH);
  hipMemsetAsync(cntO, 0, 6 * N_NODES * sizeof(int), stream);
  csrCountK<<<E0_EDGES/256, 256, 0, stream>>>(ei, ej, cntO, cntI);
  csrScanK<<<1, 256, 0, stream>>>(cntO, cntI, ofsO, ofsI);
  csrFillK<<<E0_EDGES/256, 256, 0, stream>>>(ei, ej, ofsO, ofsI, curO, curI, lstO, lstI);

  // ---- opening: fT = tanh(LN(x0T·K1^T))·K2^T ----
  transposeBF<<<dim3(N_NODES/32, CIN/32), dim3(32, 8), 0, stream>>>(x0, fh, CIN, N_NODES);
  gemmB1<64,32,32,0,0,1,0,1,false,false><<<dim3(8,128,1), 256, 0, stream>>>(
      fh, fh, CIN, 1 << 30, wH + OFF_K1, CIN,
      nullptr, uTh, nullptr, CF, 0, CIN, 1.f, 0.f, nullptr, pS, pS2,
      nullptr, nullptr, nullptr, nullptr, nullptr);
  tanhNormBF<<<256, 256, 0, stream>>>(uTh, pS, pS2);
  gemmB1<64,32,32,0,1,1,1,0,false,false><<<dim3(8,128,1), 256, 0, stream>>>(
      uTh, uTh, CF, 1 << 30, wH + OFF_K2, CF,
      fT, fTh, fh, CF, 0, CF, 1.f, 0.f, nullptr, nullptr, nullptr,
      nullptr, nullptr, nullptr, nullptr, nullptr);

  for (int L = 0; L < NLAYER; L++) {
    const ushort* k1h = wH + OFF_KN1 + (size_t)L * CF * 2 * CF;
    const ushort* k2h = wH + OFF_KN2 + (size_t)L * CF * CF;

    // Gram upper-triangle tiles, split-K=16, plain per-z partial stores,
    // fused sqSH prologue on blocks z*10+bx < 64
    gemmB1<128,64,64,0,1,0,0,0,true,true><<<dim3(10,1,16), 256, 0, stream>>>(
        fh, fh, N_NODES, 1 << 30, fh, N_NODES,
        Gp, nullptr, nullptr, CF, 65536, 256, 1.f, 0.f, nullptr, nullptr, nullptr,
        fTh, sq, sP, hP, deg);
    stdPartsK<<<STD_BLOCKS, 256, 0, stream>>>(sP, hP, Gp, sq, parts);
    edgeWK<<<E0_EDGES/16, 256, 0, stream>>>(ei, ej, fTh, sq, parts, wE, deg);
    gatherLapK<<<N_NODES/4, 256, 0, stream>>>(lstO, lstI, ofsO, ofsI, cntO, cntI,
                                              wE, deg, fTh, lapTh);
    // uT = [fT, lapT]·KN1^T (fused K=512 dual-A) + LN-stat partials
    gemmB1<64,32,32,0,0,1,0,1,false,false><<<dim3(8,128,1), 256, 0, stream>>>(
        fTh, lapTh, CF, 256, k1h, 2*CF,
        nullptr, uTh, nullptr, CF, 0, 2*CF, 1.f, 0.f, nullptr, pS, pS2,
        nullptr, nullptr, nullptr, nullptr, nullptr);
    tanhNormBF<<<256, 256, 0, stream>>>(uTh, pS, pS2);
    // fT += 0.1 · uT·KN2^T  (writes f32 fT, bf16 fTh, transposed bf16 fh)
    gemmB1<64,32,32,0,1,1,1,0,false,false><<<dim3(8,128,1), 256, 0, stream>>>(
        uTh, uTh, CF, 1 << 30, k2h, CF,
        fT, fTh, fh, CF, 0, CF, 0.1f, 1.f, nullptr, nullptr, nullptr,
        nullptr, nullptr, nullptr, nullptr, nullptr);
  }

  // ---- close: y = fT·KNclose^T ; x1 = elu(y·lin1^T+b1) ; logits ; log_softmax ----
  gemmB1<64,32,32,0,0,1,0,0,false,false><<<dim3(8,128,1), 256, 0, stream>>>(
      fTh, fTh, CF, 1 << 30, wH + OFF_KNC, CF,
      nullptr, uTh, nullptr, CF, 0, CF, 1.f, 0.f, nullptr, nullptr, nullptr,
      nullptr, nullptr, nullptr, nullptr, nullptr);
  gemmB1<64,32,32,1,0,1,0,0,false,false><<<dim3(8,128,1), 256, 0, stream>>>(
      uTh, uTh, CF, 1 << 30, wH + OFF_L1, CF,
      nullptr, lapTh, nullptr, CF, 0, CF, 1.f, 0.f, lin1b, nullptr, nullptr,
      nullptr, nullptr, nullptr, nullptr, nullptr);
  gemmB1<64,32,32,0,1,0,0,0,false,false><<<dim3(32,128,1), 256, 0, stream>>>(
      lapTh, lapTh, CF, 1 << 30, wH + OFF_L2, CF,
      logits, nullptr, nullptr, NOUT, 0, CF, 1.f, 0.f, lin2b, nullptr, nullptr,
      nullptr, nullptr, nullptr, nullptr, nullptr);
  logSoftmaxK<<<N_NODES, 256, 0, stream>>>(logits, out);
}

// Round 16
// 772.145 us; speedup vs baseline: 1.0451x; 1.0043x over previous
//
#include <hip/hip_runtime.h>
#include <hip/hip_bf16.h>

// Problem constants (fixed instance)
#define N_NODES 4096
#define CF      256
#define CIN     64
#define E0_EDGES 65536
#define NLAYER  8
#define NOUT    1024
#define CN      (CF * N_NODES)
#define STD_BLOCKS 64

typedef unsigned short ushort;
typedef __attribute__((ext_vector_type(8))) short s8v;   // 8 bf16
typedef __attribute__((ext_vector_type(4))) float f4v;   // MFMA acc

__device__ __forceinline__ ushort f2bf(float x){
  unsigned int u = __builtin_bit_cast(unsigned int, x);
  return (ushort)((u + 0x7FFFu + ((u >> 16) & 1u)) >> 16);
}
__device__ __forceinline__ float bf2f(ushort h){
  unsigned int u = ((unsigned int)h) << 16;
  return __builtin_bit_cast(float, u);
}

// ---------------- reduction helpers ----------------
__device__ __forceinline__ float waveSumF(float v){
  #pragma unroll
  for (int o = 32; o; o >>= 1) v += __shfl_xor(v, o);
  return v;
}
__device__ __forceinline__ double waveSumD(double v){
  #pragma unroll
  for (int o = 32; o; o >>= 1) v += __shfl_xor(v, o);
  return v;
}
__device__ __forceinline__ float waveMaxF(float v){
  #pragma unroll
  for (int o = 32; o; o >>= 1) v = fmaxf(v, __shfl_xor(v, o));
  return v;
}
__device__ float blockSumF(float v){
  __shared__ float sm[4];
  v = waveSumF(v);
  int l = threadIdx.x & 63, w = threadIdx.x >> 6;
  __syncthreads();
  if (l == 0) sm[w] = v;
  __syncthreads();
  return sm[0] + sm[1] + sm[2] + sm[3];
}
__device__ double blockSumD(double v){
  __shared__ double sm[4];
  v = waveSumD(v);
  int l = threadIdx.x & 63, w = threadIdx.x >> 6;
  __syncthreads();
  if (l == 0) sm[w] = v;
  __syncthreads();
  return sm[0] + sm[1] + sm[2] + sm[3];
}
__device__ float blockMaxF(float v){
  __shared__ float sm[4];
  v = waveMaxF(v);
  int l = threadIdx.x & 63, w = threadIdx.x >> 6;
  __syncthreads();
  if (l == 0) sm[w] = v;
  __syncthreads();
  return fmaxf(fmaxf(sm[0], sm[1]), fmaxf(sm[2], sm[3]));
}

// ---------------- bf16 MFMA GEMM, depth-2 prefetch, templated MT/NT/BK -------
// C[M,N] = alpha*A·B^T (+beta*Cf, +bias, act). A,B bf16 row-major K-contiguous.
// A rows split across A1/A2 at K=splitAt. Tile MTxNT; 4 waves as 2x2.
// Loads issued two tiles ahead (static ping-pong regs). One barrier per tile.
// WFH: extra transposed bf16 write. TRI: upper-triangle tiles of a 256x256
// output (MT=64: 10 tiles of 4x4 grid; MT=32: 36 tiles of 8x8 grid).
// SQSH: blocks with z*gridDim.x+bx < 64 run the fused per-node sq + s/h
// partial + deg-zero prologue.
// cStrideZ!=0: per-z split-K partials (plain store).
// NOTE (R9): do NOT fuse tanh into STORETILE (critical-path VALU, ~3x cost).
// NOTE (R10): L2-resident redundancy is free; serialized wave chains are not.
// NOTE (R13-R15): occupancy pays up to ~4 blocks/CU for these latency-bound
// GEMMs, then saturates. Sub-1-block/CU grids (old Gram: 160 blocks) are the
// worst case — spread tiles until every CU is covered.
#define MF(a,b,c) c = __builtin_amdgcn_mfma_f32_16x16x32_bf16(a, b, c, 0, 0, 0)

template<int BK, int MT, int NT, int ACT, bool WF32, bool WBF, bool WFH,
         bool MV, bool TRI, bool SQSH>
__global__ __launch_bounds__(256)
void gemmB1(const ushort* __restrict__ A1, const ushort* __restrict__ A2,
            int lda, int splitAt,
            const ushort* __restrict__ B, int ldb,
            float* __restrict__ Cf, ushort* __restrict__ Cb, ushort* __restrict__ Cfh,
            int ldc, size_t cStrideZ, int kChunk,
            float alpha, float beta, const float* __restrict__ bias,
            double* __restrict__ pS, double* __restrict__ pS2,
            const ushort* __restrict__ fThp, float* __restrict__ sqp,
            float* __restrict__ sPp, float* __restrict__ hPp,
            float* __restrict__ degp)
{
  constexpr int TPR_A = 256 / MT;                 // threads per A row
  constexpr int TPR_B = 256 / NT;
  constexpr int NCA = (MT * BK) / 2048;           // s8v chunks per thread
  constexpr int NCB = (NT * BK) / 2048;
  constexpr int MR = MT / 32, NR = NT / 32;       // frags per wave
  __shared__ ushort As[2][MT][BK + 8], Bs[2][NT][BK + 8];
  const int tid = threadIdx.x;
  const int ar = tid / TPR_A, ak = (tid % TPR_A) * (NCA * 8);
  const int br = tid / TPR_B, bk_ = (tid % TPR_B) * (NCB * 8);
  int bx = blockIdx.x, by = blockIdx.y;
  if (TRI) {
    if constexpr (MT == 64) {
      const int trT[10] = {0,0,0,0,1,1,1,2,2,3};
      const int tcT[10] = {0,1,2,3,1,2,3,2,3,3};
      by = trT[blockIdx.x]; bx = tcT[blockIdx.x];
    } else {
      const int trT[36] = {0,0,0,0,0,0,0,0, 1,1,1,1,1,1,1, 2,2,2,2,2,2,
                           3,3,3,3,3, 4,4,4,4, 5,5,5, 6,6, 7};
      const int tcT[36] = {0,1,2,3,4,5,6,7, 1,2,3,4,5,6,7, 2,3,4,5,6,7,
                           3,4,5,6,7, 4,5,6,7, 5,6,7, 6,7, 7};
      by = trT[blockIdx.x]; bx = tcT[blockIdx.x];
    }
  }

  if constexpr (SQSH) {
    __shared__ float smS[4][256], smH[4][256];
    int g = blockIdx.z * gridDim.x + blockIdx.x;
    if (g < 64) {
      int w = tid >> 6, ln = tid & 63;
      if (tid < 64) degp[g * 64 + tid] = 0.0f;
      float sA[4] = {0,0,0,0}, hA[4] = {0,0,0,0};
      for (int rr = 0; rr < 16; rr++) {
        int n = g * 64 + rr * 4 + w;
        ushort4 u = ((const ushort4*)(fThp + (size_t)n * CF))[ln];
        float x0 = bf2f(u.x), x1 = bf2f(u.y), x2 = bf2f(u.z), x3 = bf2f(u.w);
        float q = waveSumF(x0*x0 + x1*x1 + x2*x2 + x3*x3);
        if (ln == 0) sqp[n] = q;
        sA[0] += x0; sA[1] += x1; sA[2] += x2; sA[3] += x3;
        hA[0] += x0*q; hA[1] += x1*q; hA[2] += x2*q; hA[3] += x3*q;
      }
      #pragma unroll
      for (int k = 0; k < 4; k++) { smS[w][ln*4+k] = sA[k]; smH[w][ln*4+k] = hA[k]; }
      __syncthreads();
      sPp[(size_t)g * 256 + tid] = smS[0][tid] + smS[1][tid] + smS[2][tid] + smS[3][tid];
      hPp[(size_t)g * 256 + tid] = smH[0][tid] + smH[1][tid] + smH[2][tid] + smH[3][tid];
    }
  }

  const int row0 = by * MT, col0 = bx * NT;
  const int kStart = blockIdx.z * kChunk;
  const int nT = kChunk / BK;

  const int wid = tid >> 6, lane = tid & 63;
  const int wr = (wid >> 1) * (MT / 2), wc = (wid & 1) * (NT / 2);
  const int fr = lane & 15, fk = (lane >> 4) * 8;

  f4v acc[MR][NR] = {};
  s8v rA0[NCA], rB0[NCB], rA1[NCA], rB1[NCB];

#define LOADTILE(T, RA, RB) { \
    int k0 = kStart + (T) * BK; \
    const ushort* Ag; int kk; \
    if (k0 < splitAt) { Ag = A1; kk = k0; } else { Ag = A2; kk = k0 - splitAt; } \
    size_t aoff = (size_t)(row0 + ar) * lda + kk + ak; \
    size_t boff = (size_t)(col0 + br) * ldb + k0 + bk_; \
    _Pragma("unroll") \
    for (int c = 0; c < NCA; c++) RA[c] = *(const s8v*)(Ag + aoff + 8 * c); \
    _Pragma("unroll") \
    for (int c = 0; c < NCB; c++) RB[c] = *(const s8v*)(B + boff + 8 * c); }

#define STORETILE(BUF, RA, RB) { \
    _Pragma("unroll") \
    for (int c = 0; c < NCA; c++) *(s8v*)&As[BUF][ar][ak + 8 * c] = RA[c]; \
    _Pragma("unroll") \
    for (int c = 0; c < NCB; c++) *(s8v*)&Bs[BUF][br][bk_ + 8 * c] = RB[c]; }

#define MFMAT(BUF) { \
    _Pragma("unroll") \
    for (int ks = 0; ks < BK; ks += 32) { \
      s8v a[MR], b[NR]; \
      _Pragma("unroll") \
      for (int m = 0; m < MR; m++) a[m] = *(const s8v*)&As[BUF][wr + m*16 + fr][ks + fk]; \
      _Pragma("unroll") \
      for (int n = 0; n < NR; n++) b[n] = *(const s8v*)&Bs[BUF][wc + n*16 + fr][ks + fk]; \
      _Pragma("unroll") \
      for (int m = 0; m < MR; m++) \
        _Pragma("unroll") \
        for (int n = 0; n < NR; n++) MF(a[m], b[n], acc[m][n]); } }

  LOADTILE(0, rA0, rB0);
  if (nT > 1) LOADTILE(1, rA1, rB1);
  STORETILE(0, rA0, rB0);

  for (int t = 0; t < nT; t += 2) {
    __syncthreads();                       // lds0(tile t) visible; old reads done
    if (t + 2 < nT) LOADTILE(t + 2, rA0, rB0);
    MFMAT(0);
    if (t + 1 < nT) {
      STORETILE(1, rA1, rB1);              // lds1 last read before top barrier
      __syncthreads();
      if (t + 3 < nT) LOADTILE(t + 3, rA1, rB1);
      MFMAT(1);
      if (t + 2 < nT) STORETILE(0, rA0, rB0);  // lds0 last read before mid barrier
    }
  }
#undef LOADTILE
#undef STORETILE
#undef MFMAT

  double s = 0, s2 = 0;
  #pragma unroll
  for (int m = 0; m < MR; m++)
    #pragma unroll
    for (int n = 0; n < NR; n++) {
      const int rowb = row0 + wr + m * 16 + (lane >> 4) * 4;
      const int col  = col0 + wc + n * 16 + fr;
      ushort4 hv;
      #pragma unroll
      for (int q = 0; q < 4; q++) {
        size_t cidx = (size_t)(rowb + q) * ldc + col;
        float v = alpha * acc[m][n][q];
        if (cStrideZ) {
          Cf[blockIdx.z * cStrideZ + cidx] = v;
        } else {
          if (beta != 0.0f) v += beta * Cf[cidx];
          if (bias) v += bias[col];
          if (ACT == 1) v = (v > 0.0f) ? v : expm1f(v);
          if (WF32) Cf[cidx] = v;
          if (WBF)  Cb[cidx] = f2bf(v);
          if (WFH)  ((ushort*)&hv)[q] = f2bf(v);
          if (MV)   { s += v; s2 += (double)v * v; }
        }
      }
      if (WFH && !cStrideZ)
        *(ushort4*)(Cfh + (size_t)col * N_NODES + rowb) = hv;
    }
  if (MV) {
    s  = blockSumD(s);
    s2 = blockSumD(s2);
    if (tid == 0) {
      int bid = blockIdx.y * gridDim.x + blockIdx.x;   // stats grids are <=1024 blocks
      pS[bid] = s; pS2[bid] = s2;
    }
  }
}

// ---------------- weight f32 -> bf16 (once per launch) ----------------------
#define OFF_K1   0
#define OFF_K2   16384
#define OFF_KNC  81920
#define OFF_KN1  147456
#define OFF_KN2  1196032
#define OFF_L1   1720320
#define OFF_L2   1785856
#define NW_TOT   2048000

__global__ __launch_bounds__(256)
void prepWK(const float* s0, const float* s1, const float* s2, const float* s3,
            const float* s4, const float* s5, const float* s6,
            ushort* __restrict__ h)
{
  const int sizes[7] = {16384, 65536, 65536, 1048576, 524288, 65536, 262144};
  const int offs[7]  = {OFF_K1, OFF_K2, OFF_KNC, OFF_KN1, OFF_KN2, OFF_L1, OFF_L2};
  int seg = blockIdx.y;
  const float* src = seg==0?s0: seg==1?s1: seg==2?s2: seg==3?s3: seg==4?s4: seg==5?s5: s6;
  int n = sizes[seg], off = offs[seg];
  for (int i = blockIdx.x * 256 + threadIdx.x; i < n; i += gridDim.x * 256)
    h[off + i] = f2bf(src[i]);
}

// ---------------- transpose f32 [R][Cc] -> bf16 [Cc][R] (open only) ----------
__global__ __launch_bounds__(256)
void transposeBF(const float* __restrict__ in, ushort* __restrict__ outh, int R, int Cc)
{
  __shared__ float t[32][33];
  int x  = blockIdx.x * 32 + threadIdx.x;
  int y0 = blockIdx.y * 32;
  for (int dy = threadIdx.y; dy < 32; dy += 8)
    t[dy][threadIdx.x] = in[(size_t)(y0 + dy) * Cc + x];
  __syncthreads();
  int ox  = y0 + threadIdx.x;
  int oy0 = blockIdx.x * 32;
  for (int dy = threadIdx.y; dy < 32; dy += 8)
    outh[(size_t)(oy0 + dy) * R + ox] = f2bf(t[threadIdx.x][dy]);
}

// ---------------- whole-tensor tanh-LN in place on bf16 ---------------------
// 1024 blocks, one ushort4 per thread (exact cover of CN). Stats partial
// arrays are 1024 entries; each of the first 256 threads sums 4.
__global__ __launch_bounds__(256)
void tanhNormBF(ushort* __restrict__ h, const double* __restrict__ pS,
                const double* __restrict__ pS2)
{
  __shared__ float bc[2];
  double a = pS[threadIdx.x] + pS[threadIdx.x + 256] +
             pS[threadIdx.x + 512] + pS[threadIdx.x + 768];
  double b = pS2[threadIdx.x] + pS2[threadIdx.x + 256] +
             pS2[threadIdx.x + 512] + pS2[threadIdx.x + 768];
  a = blockSumD(a);
  b = blockSumD(b);
  if (threadIdx.x == 0) {
    double m   = a / (double)CN;
    double var = b / (double)CN - m * m;
    bc[0] = (float)m;
    bc[1] = (float)(1.0 / sqrt(var + 1e-5));
  }
  __syncthreads();
  float mf = bc[0], rs = bc[1];
  size_t idx = ((size_t)blockIdx.x * 256 + threadIdx.x) * 4;
  ushort4 hv = *(ushort4*)(h + idx);
  hv.x = f2bf(tanhf((bf2f(hv.x) - mf) * rs));
  hv.y = f2bf(tanhf((bf2f(hv.y) - mf) * rs));
  hv.z = f2bf(tanhf((bf2f(hv.z) - mf) * rs));
  hv.w = f2bf(tanhf((bf2f(hv.w) - mf) * rs));
  *(ushort4*)(h + idx) = hv;
}

// ---------------- std(D) closed form: 64-block partials (upper-tri Gp) -------
__global__ __launch_bounds__(256)
void stdPartsK(const float* __restrict__ sP, const float* __restrict__ hP,
               const float* __restrict__ Gp, const float* __restrict__ sq,
               double* __restrict__ parts)
{
  int b = blockIdx.x, t = threadIdx.x;
  double S1 = 0, S2 = 0, sd = 0, hd = 0, gf = 0;
  for (int i = b * 256 + t; i < N_NODES; i += STD_BLOCKS * 256) {
    double q = sq[i]; S1 += q; S2 += q * q;
  }
  if (b == 0) {
    float sv = 0, hv = 0;
    for (int p = 0; p < 64; p++) { sv += sP[p * 256 + t]; hv += hP[p * 256 + t]; }
    sd = (double)sv * sv; hd = (double)hv * sv;
  }
  for (int i = b * 256 + t; i < CF * CF; i += STD_BLOCKS * 256) {
    int r = i >> 8, c = i & 255;
    if (r > c) continue;               // only upper-triangle tiles were computed
    double g = 0;
    #pragma unroll 4
    for (int z = 0; z < 16; z++) g += Gp[(size_t)z * 65536 + i];
    gf += (r == c) ? g * g : 2.0 * g * g;
  }
  S1 = blockSumD(S1);
  S2 = blockSumD(S2);
  sd = blockSumD(sd);
  hd = blockSumD(hd);
  gf = blockSumD(gf);
  if (t == 0) {
    parts[0 * STD_BLOCKS + b] = S1;
    parts[1 * STD_BLOCKS + b] = S2;
    parts[2 * STD_BLOCKS + b] = sd;
    parts[3 * STD_BLOCKS + b] = hd;
    parts[4 * STD_BLOCKS + b] = gf;
  }
}

// ---------------- edge affinities + inline std finalize + deg atomics --------
// 4096 blocks, 4 edges per wave.
__global__ __launch_bounds__(256)
void edgeWK(const int* __restrict__ ei, const int* __restrict__ ej,
            const ushort* __restrict__ fTh, const float* __restrict__ sq,
            const double* __restrict__ parts, float* __restrict__ wE,
            float* __restrict__ deg)
{
  __shared__ float c0s;
  if (threadIdx.x < 64) {
    int l = threadIdx.x;
    double v0 = waveSumD(parts[0 * STD_BLOCKS + l]);
    double v1 = waveSumD(parts[1 * STD_BLOCKS + l]);
    double v2 = waveSumD(parts[2 * STD_BLOCKS + l]);
    double v3 = waveSumD(parts[3 * STD_BLOCKS + l]);
    double v4 = waveSumD(parts[4 * STD_BLOCKS + l]);
    if (l == 0) {
      double NN = (double)N_NODES;
      double sum1 = 2.0 * NN * v0 - 2.0 * v2;
      double sum2 = 2.0 * NN * v1 + 2.0 * v0 * v0 + 4.0 * v4 - 8.0 * v3;
      double n2 = NN * NN;
      double var = (sum2 - sum1 * sum1 / n2) / (n2 - 1.0);
      double sdev = sqrt(var > 0 ? var : 0);
      c0s = (float)(-2.0 / sdev);
    }
  }
  __syncthreads();
  float c0 = c0s;
  int w = threadIdx.x >> 6, lane = threadIdx.x & 63;
  int e0 = (blockIdx.x * 4 + w) * 4;
  for (int q = 0; q < 4; q++) {
    int e = e0 + q;
    int i = ei[e], j = ej[e];
    ushort4 ua = ((const ushort4*)(fTh + (size_t)i * CF))[lane];
    ushort4 ub = ((const ushort4*)(fTh + (size_t)j * CF))[lane];
    float d = waveSumF(bf2f(ua.x)*bf2f(ub.x) + bf2f(ua.y)*bf2f(ub.y) +
                       bf2f(ua.z)*bf2f(ub.z) + bf2f(ua.w)*bf2f(ub.w));
    if (lane == 0) {
      float dist = fmaxf(sq[i] + sq[j] - 2.0f * d, 0.0f);
      float ww = expf(c0 * dist);
      wE[e] = ww;
      unsafeAtomicAdd(&deg[j], ww);
    }
  }
}

// ---------------- CSR build (edge list is a fixed input) ---------------------
__global__ __launch_bounds__(256)
void csrCountK(const int* __restrict__ ei, const int* __restrict__ ej,
               int* __restrict__ cntO, int* __restrict__ cntI)
{
  int e = blockIdx.x * 256 + threadIdx.x;
  atomicAdd(&cntO[ei[e]], 1);
  atomicAdd(&cntI[ej[e]], 1);
}

__global__ __launch_bounds__(256)
void csrScanK(const int* __restrict__ cntO, const int* __restrict__ cntI,
              int* __restrict__ ofsO, int* __restrict__ ofsI)
{
  __shared__ int smO[256], smI[256];
  int t = threadIdx.x;
  int lo[16], li[16];
  int sO = 0, sI = 0;
  #pragma unroll
  for (int k = 0; k < 16; k++) {
    lo[k] = cntO[t * 16 + k]; li[k] = cntI[t * 16 + k];
    sO += lo[k]; sI += li[k];
  }
  smO[t] = sO; smI[t] = sI;
  __syncthreads();
  for (int off = 1; off < 256; off <<= 1) {
    int aO = (t >= off) ? smO[t - off] : 0;
    int aI = (t >= off) ? smI[t - off] : 0;
    __syncthreads();
    smO[t] += aO; smI[t] += aI;
    __syncthreads();
  }
  int bO = smO[t] - sO;
  int bI = smI[t] - sI;
  #pragma unroll
  for (int k = 0; k < 16; k++) {
    ofsO[t * 16 + k] = bO; bO += lo[k];
    ofsI[t * 16 + k] = bI; bI += li[k];
  }
}

__global__ __launch_bounds__(256)
void csrFillK(const int* __restrict__ ei, const int* __restrict__ ej,
              const int* __restrict__ ofsO, const int* __restrict__ ofsI,
              int* __restrict__ curO, int* __restrict__ curI,
              int2* __restrict__ lstO, int2* __restrict__ lstI)
{
  int e = blockIdx.x * 256 + threadIdx.x;
  int i = ei[e], j = ej[e];
  int p = atomicAdd(&curO[i], 1); lstO[ofsO[i] + p] = make_int2(j, e);
  int q = atomicAdd(&curI[j], 1); lstI[ofsI[j] + q] = make_int2(i, e);
}

// ---------------- graph Laplacian gather, fused W² (wave per node) -----------
__global__ __launch_bounds__(256)
void gatherLapK(const int2* __restrict__ lstO, const int2* __restrict__ lstI,
                const int* __restrict__ ofsO, const int* __restrict__ ofsI,
                const int* __restrict__ cntO, const int* __restrict__ cntI,
                const float* __restrict__ wE, const float* __restrict__ deg,
                const ushort* __restrict__ fTh, ushort* __restrict__ lapTh)
{
  int w = threadIdx.x >> 6, lane = threadIdx.x & 63;
  int n = blockIdx.x * 4 + w;
  ushort4 u = ((const ushort4*)(fTh + (size_t)n * CF))[lane];
  float o0 = bf2f(u.x), o1 = bf2f(u.y), o2 = bf2f(u.z), o3 = bf2f(u.w);
  float dn = rsqrtf(1.0f + deg[n]);
  float a0 = 0, a1 = 0, a2 = 0, a3 = 0;
  int p0 = ofsO[n], pc = cntO[n];
  for (int k = 0; k < pc; k++) {
    int2 oe = lstO[p0 + k];
    float W = dn * wE[oe.y] * rsqrtf(1.0f + deg[oe.x]);
    float W2 = W * W;
    ushort4 v = ((const ushort4*)(fTh + (size_t)oe.x * CF))[lane];
    a0 += W2 * (o0 - bf2f(v.x)); a1 += W2 * (o1 - bf2f(v.y));
    a2 += W2 * (o2 - bf2f(v.z)); a3 += W2 * (o3 - bf2f(v.w));
  }
  int q0 = ofsI[n], qc = cntI[n];
  for (int k = 0; k < qc; k++) {
    int2 oe = lstI[q0 + k];
    float W = dn * wE[oe.y] * rsqrtf(1.0f + deg[oe.x]);
    float W2 = W * W;
    ushort4 v = ((const ushort4*)(fTh + (size_t)oe.x * CF))[lane];
    a0 += W2 * (o0 - bf2f(v.x)); a1 += W2 * (o1 - bf2f(v.y));
    a2 += W2 * (o2 - bf2f(v.z)); a3 += W2 * (o3 - bf2f(v.w));
  }
  ushort4 rv;
  rv.x = f2bf(a0); rv.y = f2bf(a1); rv.z = f2bf(a2); rv.w = f2bf(a3);
  ((ushort4*)(lapTh + (size_t)n * CF))[lane] = rv;
}

// ---------------- row log-softmax ----------------
__global__ __launch_bounds__(256)
void logSoftmaxK(const float* __restrict__ logits, float* __restrict__ out)
{
  int n = blockIdx.x;
  const float* row = logits + (size_t)n * NOUT;
  float mx = -1e30f;
  for (int o = threadIdx.x; o < NOUT; o += 256) mx = fmaxf(mx, row[o]);
  mx = blockMaxF(mx);
  float se = 0;
  for (int o = threadIdx.x; o < NOUT; o += 256) se += expf(row[o] - mx);
  se = blockSumF(se);
  float lse = mx + logf(se);
  for (int o = threadIdx.x; o < NOUT; o += 256) out[(size_t)n * NOUT + o] = row[o] - lse;
}

extern "C" void kernel_launch(void* const* d_in, const int* in_sizes, int n_in,
                              void* d_out, int out_size, void* d_ws, size_t ws_size,
                              hipStream_t stream)
{
  (void)in_sizes; (void)n_in; (void)out_size; (void)ws_size;
  const float* x0      = (const float*)d_in[0];
  const float* K1      = (const float*)d_in[1];
  const float* K2      = (const float*)d_in[2];
  const float* KNclose = (const float*)d_in[3];
  const float* KN1     = (const float*)d_in[4];
  const float* KN2     = (const float*)d_in[5];
  const float* lin1w   = (const float*)d_in[6];
  const float* lin1b   = (const float*)d_in[7];
  const float* lin2w   = (const float*)d_in[8];
  const float* lin2b   = (const float*)d_in[9];
  const int*   ei      = (const int*)d_in[10];
  const int*   ej      = (const int*)d_in[11];
  float* out = (float*)d_out;

  // ---------------- workspace layout ----------------
  float* base   = (float*)d_ws;
  float* fT     = base;                     // [N][CF] f32 residual features
  float* logits = fT + (size_t)CN;          // [N][NOUT]
  float* Gp     = logits + 4 * (size_t)CN;  // [16][256*256] Gram split-K partials
  float* sq     = Gp + (size_t)CN;          // [N]
  float* deg    = sq + N_NODES;             // [N]
  float* sP     = deg + N_NODES;            // [64][256]
  float* hP     = sP + 64 * 256;            // [64][256]
  float* wE     = hP + 64 * 256;            // [E0]
  double* pS    = (double*)(wE + E0_EDGES + 2);  // [1024]
  double* pS2   = pS + 1024;                // [1024]
  double* parts = pS2 + 1024;               // [5*64]

  ushort* u0 = (ushort*)(((uintptr_t)(parts + 5 * STD_BLOCKS) + 15) & ~(uintptr_t)15);
  ushort* fTh   = u0;                       // [N][CF] bf16 features
  ushort* fh    = fTh + (size_t)CN;         // [CF][N] transposed bf16 (xt at open)
  ushort* lapTh = fh + (size_t)CN;          // lap bf16; x1 at close
  ushort* uTh   = lapTh + (size_t)CN;       // intermediate bf16; y at close
  ushort* wH    = uTh + (size_t)CN;         // all weights bf16
  int* ib = (int*)(((uintptr_t)(wH + NW_TOT) + 15) & ~(uintptr_t)15);
  int*  cntO = ib;
  int*  cntI = cntO + N_NODES;
  int*  ofsO = cntI + N_NODES;
  int*  ofsI = ofsO + N_NODES;
  int*  curO = ofsI + N_NODES;
  int*  curI = curO + N_NODES;
  int2* lstO = (int2*)(curI + N_NODES);
  int2* lstI = lstO + E0_EDGES;

  // ---- one-time: weight bf16 + CSR ----
  prepWK<<<dim3(64, 7), 256, 0, stream>>>(K1, K2, KNclose, KN1, KN2, lin1w, lin2w, wH);
  hipMemsetAsync(cntO, 0, 6 * N_NODES * sizeof(int), stream);
  csrCountK<<<E0_EDGES/256, 256, 0, stream>>>(ei, ej, cntO, cntI);
  csrScanK<<<1, 256, 0, stream>>>(cntO, cntI, ofsO, ofsI);
  csrFillK<<<E0_EDGES/256, 256, 0, stream>>>(ei, ej, ofsO, ofsI, curO, curI, lstO, lstI);

  // ---- opening: fT = tanh(LN(x0T·K1^T))·K2^T ----
  transposeBF<<<dim3(N_NODES/32, CIN/32), dim3(32, 8), 0, stream>>>(x0, fh, CIN, N_NODES);
  gemmB1<64,32,32,0,0,1,0,1,false,false><<<dim3(8,128,1), 256, 0, stream>>>(
      fh, fh, CIN, 1 << 30, wH + OFF_K1, CIN,
      nullptr, uTh, nullptr, CF, 0, CIN, 1.f, 0.f, nullptr, pS, pS2,
      nullptr, nullptr, nullptr, nullptr, nullptr);
  tanhNormBF<<<1024, 256, 0, stream>>>(uTh, pS, pS2);
  gemmB1<64,32,32,0,1,1,1,0,false,false><<<dim3(8,128,1), 256, 0, stream>>>(
      uTh, uTh, CF, 1 << 30, wH + OFF_K2, CF,
      fT, fTh, fh, CF, 0, CF, 1.f, 0.f, nullptr, nullptr, nullptr,
      nullptr, nullptr, nullptr, nullptr, nullptr);

  for (int L = 0; L < NLAYER; L++) {
    const ushort* k1h = wH + OFF_KN1 + (size_t)L * CF * 2 * CF;
    const ushort* k2h = wH + OFF_KN2 + (size_t)L * CF * CF;

    // Gram upper-triangle 32x32 tiles (36 of 8x8 grid), split-K=16 ->
    // 576 blocks (vs old 160: sub-1-block/CU was the last latency hole),
    // fused sqSH prologue on blocks z*36+bx < 64
    gemmB1<64,32,32,0,1,0,0,0,true,true><<<dim3(36,1,16), 256, 0, stream>>>(
        fh, fh, N_NODES, 1 << 30, fh, N_NODES,
        Gp, nullptr, nullptr, CF, 65536, 256, 1.f, 0.f, nullptr, nullptr, nullptr,
        fTh, sq, sP, hP, deg);
    stdPartsK<<<STD_BLOCKS, 256, 0, stream>>>(sP, hP, Gp, sq, parts);
    edgeWK<<<E0_EDGES/16, 256, 0, stream>>>(ei, ej, fTh, sq, parts, wE, deg);
    gatherLapK<<<N_NODES/4, 256, 0, stream>>>(lstO, lstI, ofsO, ofsI, cntO, cntI,
                                              wE, deg, fTh, lapTh);
    // uT = [fT, lapT]·KN1^T (fused K=512 dual-A) + LN-stat partials
    gemmB1<64,32,32,0,0,1,0,1,false,false><<<dim3(8,128,1), 256, 0, stream>>>(
        fTh, lapTh, CF, 256, k1h, 2*CF,
        nullptr, uTh, nullptr, CF, 0, 2*CF, 1.f, 0.f, nullptr, pS, pS2,
        nullptr, nullptr, nullptr, nullptr, nullptr);
    tanhNormBF<<<1024, 256, 0, stream>>>(uTh, pS, pS2);
    // fT += 0.1 · uT·KN2^T  (writes f32 fT, bf16 fTh, transposed bf16 fh)
    gemmB1<64,32,32,0,1,1,1,0,false,false><<<dim3(8,128,1), 256, 0, stream>>>(
        uTh, uTh, CF, 1 << 30, k2h, CF,
        fT, fTh, fh, CF, 0, CF, 0.1f, 1.f, nullptr, nullptr, nullptr,
        nullptr, nullptr, nullptr, nullptr, nullptr);
  }

  // ---- close: y = fT·KNclose^T ; x1 = elu(y·lin1^T+b1) ; logits ; log_softmax ----
  gemmB1<64,32,32,0,0,1,0,0,false,false><<<dim3(8,128,1), 256, 0, stream>>>(
      fTh, fTh, CF, 1 << 30, wH + OFF_KNC, CF,
      nullptr, uTh, nullptr, CF, 0, CF, 1.f, 0.f, nullptr, nullptr, nullptr,
      nullptr, nullptr, nullptr, nullptr, nullptr);
  gemmB1<64,32,32,1,0,1,0,0,false,false><<<dim3(8,128,1), 256, 0, stream>>>(
      uTh, uTh, CF, 1 << 30, wH + OFF_L1, CF,
      nullptr, lapTh, nullptr, CF, 0, CF, 1.f, 0.f, lin1b, nullptr, nullptr,
      nullptr, nullptr, nullptr, nullptr, nullptr);
  gemmB1<64,32,32,0,1,0,0,0,false,false><<<dim3(32,128,1), 256, 0, stream>>>(
      lapTh, lapTh, CF, 1 << 30, wH + OFF_L2, CF,
      logits, nullptr, nullptr, NOUT, 0, CF, 1.f, 0.f, lin2b, nullptr, nullptr,
      nullptr, nullptr, nullptr, nullptr, nullptr);
  logSoftmaxK<<<N_NODES, 256, 0, stream>>>(logits, out);
}